// Round 2
// baseline (3718.360 us; speedup 1.0000x reference)
//
#include <hip/hip_runtime.h>
#include <hip/hip_bf16.h>

typedef __hip_bfloat16 bf16;
typedef __attribute__((ext_vector_type(8))) short short8;   // 8 x bf16 (4 VGPRs)
typedef __attribute__((ext_vector_type(4))) float f32x4;

#define Hdim 512
#define Bdim 512
#define Tdim 64
#define Fdim 64
#define NC   4

__device__ __forceinline__ float sigmoidf_(float x){ return 1.f/(1.f + __expf(-x)); }

// ---------------- fp32 -> bf16 pack (weights) ----------------
__global__ __launch_bounds__(256) void pack_kernel(const float* __restrict__ src,
                                                   bf16* __restrict__ dst, int n){
  int idx = (blockIdx.x*256 + threadIdx.x)*4;
  if (idx < n){
    float4 v = *(const float4*)(src + idx);
    dst[idx+0] = (bf16)v.x;
    dst[idx+1] = (bf16)v.y;
    dst[idx+2] = (bf16)v.z;
    dst[idx+3] = (bf16)v.w;
  }
}

// ---------------- transpose data [B][F][T] fp32 -> dataT [T][B][F] bf16 ----------------
__global__ __launch_bounds__(256) void transpose_kernel(const float* __restrict__ data,
                                                        bf16* __restrict__ dataT){
  __shared__ bf16 tile[64*65];
  int b = blockIdx.x;
  int tid = threadIdx.x;
  for (int i = 0; i < 16; ++i){
    int idx = tid + i*256;
    int f = idx >> 6, t = idx & 63;
    tile[f*65 + t] = (bf16)data[(b*64 + f)*64 + t];
  }
  __syncthreads();
  for (int i = 0; i < 16; ++i){
    int idx = tid + i*256;
    int t = idx >> 6, f = idx & 63;
    dataT[(t*Bdim + b)*64 + f] = tile[f*65 + t];
  }
}

// ---------------- init h state (fp32 + bf16 shadow), zero dot buffer ----------------
__global__ __launch_bounds__(256) void init_kernel(const float* __restrict__ init_h,
                            float* __restrict__ h_f,
                            bf16* __restrict__ h_bf, float* __restrict__ dots){
  int idx = blockIdx.x*256 + threadIdx.x;          // 0 .. 4*512*512-1
  int src = idx & (Bdim*Hdim - 1);                 // broadcast over k
  float v = init_h[src];
  h_f[idx]  = v;
  h_bf[idx] = (bf16)v;
  if (idx < NC*Tdim*Bdim) dots[idx] = 0.f;
}

// ---------------- input projection: x_seq[s][k][b][h] = relu(dataT[src_t] @ fc_in_W[k]^T + b)
// time reversal for cells 2,3 baked in via src_t.
__global__ __launch_bounds__(256) void proj_kernel(const bf16* __restrict__ dataT,
    const bf16* __restrict__ fc_in_W, const float* __restrict__ fc_in_b,
    bf16* __restrict__ x_seq){
  __shared__ short ldsA[64*72];     // 64 b-rows x 64 f   (stride 72 kills bank conflicts)
  __shared__ short ldsW[128*72];    // 128 o-rows x 64 f
  int blk = blockIdx.x;
  int s  = blk >> 7;
  int k  = (blk >> 5) & 3;
  int bt = (blk >> 2) & 7;
  int on = blk & 3;
  int tid = threadIdx.x;
  int lane = tid & 63, wid = tid >> 6;
  int quad = lane >> 4, l16 = lane & 15;
  int src_t = (k < 2) ? s : (Tdim - 1 - s);

  const short* Ag = (const short*)(dataT + (src_t*Bdim + bt*64)*Fdim);
  #pragma unroll
  for (int i = 0; i < 2; ++i){
    int c = tid + i*256; int r = c >> 3, off = c & 7;
    *(int4*)(&ldsA[r*72 + off*8]) = *(const int4*)(&Ag[r*64 + off*8]);
  }
  const short* Wg = (const short*)(fc_in_W + (k*Hdim + on*128)*Fdim);
  #pragma unroll
  for (int i = 0; i < 4; ++i){
    int c = tid + i*256; int r = c >> 3, off = c & 7;
    *(int4*)(&ldsW[r*72 + off*8]) = *(const int4*)(&Wg[r*64 + off*8]);
  }
  __syncthreads();

  f32x4 acc[2][4];
  #pragma unroll
  for (int nt=0; nt<2; ++nt)
    #pragma unroll
    for (int rb=0; rb<4; ++rb) acc[nt][rb] = (f32x4){0.f,0.f,0.f,0.f};

  #pragma unroll
  for (int kk = 0; kk < 2; ++kk){
    int io = kk*32 + quad*8;
    short8 a[4];
    #pragma unroll
    for (int rb=0; rb<4; ++rb) a[rb] = *(const short8*)(&ldsA[(rb*16+l16)*72 + io]);
    #pragma unroll
    for (int nt=0; nt<2; ++nt){
      short8 bw = *(const short8*)(&ldsW[(wid*32 + nt*16 + l16)*72 + io]);
      #pragma unroll
      for (int rb=0; rb<4; ++rb)
        acc[nt][rb] = __builtin_amdgcn_mfma_f32_16x16x32_bf16(a[rb], bw, acc[nt][rb], 0,0,0);
    }
  }

  #pragma unroll
  for (int nt=0; nt<2; ++nt){
    int o = on*128 + wid*32 + nt*16 + l16;
    float bias = fc_in_b[k*Hdim + o];
    #pragma unroll
    for (int rb=0; rb<4; ++rb){
      #pragma unroll
      for (int reg=0; reg<4; ++reg){
        int b = bt*64 + rb*16 + quad*4 + reg;  // C/D: row = quad*4+reg (m89-verified)
        float v = acc[nt][rb][reg] + bias;
        v = v > 0.f ? v : 0.f;
        x_seq[((size_t)(s*NC + k)*Bdim + b)*Hdim + o] = (bf16)v;
      }
    }
  }
}

// ---------------- one GRU time step, all 4 cells, fused gates + h update + output dot
// grid 256 = k(4) x btile(8) x otile(8); block 256 = 4 waves; 64x64 tile, BK=64.
__global__ __launch_bounds__(256) void step_kernel(
    const bf16* __restrict__ x_seq,
    const bf16* __restrict__ h_in_bf, const float* __restrict__ h_in_f,
    bf16* __restrict__ h_out_bf, float* __restrict__ h_out_f,
    const bf16* __restrict__ Wih, const bf16* __restrict__ Whh,
    const float* __restrict__ bih, const float* __restrict__ bhh,
    const float* __restrict__ fc_out_W,
    float* __restrict__ dots, int s)
{
  __shared__ short ldsIn[64*72];
  __shared__ short ldsW[3][64*72];

  int blk = blockIdx.x;
  int k  = blk >> 6;
  int bt = (blk >> 3) & 7;
  int ot = blk & 7;
  int tid = threadIdx.x;
  int lane = tid & 63, wid = tid >> 6;
  int quad = lane >> 4, l16 = lane & 15;

  // r,z accumulate x-side AND h-side (concat inner-dim trick); n needs them split.
  f32x4 acc_r[4], acc_z[4], acc_n[2][4];
  #pragma unroll
  for (int rb=0;rb<4;++rb){
    acc_r[rb]=(f32x4){0.f,0.f,0.f,0.f}; acc_z[rb]=(f32x4){0.f,0.f,0.f,0.f};
    acc_n[0][rb]=(f32x4){0.f,0.f,0.f,0.f}; acc_n[1][rb]=(f32x4){0.f,0.f,0.f,0.f};
  }

  for (int side = 0; side < 2; ++side){
    const short* in_g = (const short*)(side ? (h_in_bf + (size_t)(k*Bdim + bt*64)*Hdim)
                                            : (x_seq + ((size_t)(s*NC + k)*Bdim + bt*64)*Hdim));
    const short* w_g  = (const short*)((side ? Whh : Wih) + (size_t)(k*3*Hdim + ot*64)*Hdim);

    for (int ic = 0; ic < 8; ++ic){
      __syncthreads();
      int ibase = ic*64;
      #pragma unroll
      for (int i = 0; i < 2; ++i){
        int c = tid + i*256; int r = c >> 3, off = c & 7;
        *(int4*)(&ldsIn[r*72 + off*8]) = *(const int4*)(&in_g[r*Hdim + ibase + off*8]);
      }
      #pragma unroll
      for (int p = 0; p < 3; ++p){
        #pragma unroll
        for (int i = 0; i < 2; ++i){
          int c = tid + i*256; int r = c >> 3, off = c & 7;
          *(int4*)(&ldsW[p][r*72 + off*8]) =
              *(const int4*)(&w_g[(size_t)(p*Hdim + r)*Hdim + ibase + off*8]);
        }
      }
      __syncthreads();
      #pragma unroll
      for (int kk = 0; kk < 2; ++kk){
        int io = kk*32 + quad*8;
        short8 brf = *(const short8*)(&ldsW[0][(wid*16 + l16)*72 + io]);
        short8 bzf = *(const short8*)(&ldsW[1][(wid*16 + l16)*72 + io]);
        short8 bnf = *(const short8*)(&ldsW[2][(wid*16 + l16)*72 + io]);
        #pragma unroll
        for (int rb = 0; rb < 4; ++rb){
          short8 a = *(const short8*)(&ldsIn[(rb*16 + l16)*72 + io]);
          acc_r[rb] = __builtin_amdgcn_mfma_f32_16x16x32_bf16(a, brf, acc_r[rb], 0,0,0);
          acc_z[rb] = __builtin_amdgcn_mfma_f32_16x16x32_bf16(a, bzf, acc_z[rb], 0,0,0);
          acc_n[side][rb] = __builtin_amdgcn_mfma_f32_16x16x32_bf16(a, bnf, acc_n[side][rb], 0,0,0);
        }
      }
    }
  }

  int o = ot*64 + wid*16 + l16;
  float br  = bih[k*3*Hdim + o] + bhh[k*3*Hdim + o];
  float bz  = bih[k*3*Hdim + Hdim + o] + bhh[k*3*Hdim + Hdim + o];
  float bnx = bih[k*3*Hdim + 2*Hdim + o];
  float bnh = bhh[k*3*Hdim + 2*Hdim + o];
  float wout = fc_out_W[(k & 1)*Hdim + o];
  int tmap = (k < 2) ? s : (Tdim - 1 - s);

  #pragma unroll
  for (int rb = 0; rb < 4; ++rb){
    #pragma unroll
    for (int reg = 0; reg < 4; ++reg){
      int b = bt*64 + rb*16 + quad*4 + reg;
      size_t hidx = (size_t)(k*Bdim + b)*Hdim + o;
      float r = sigmoidf_(acc_r[rb][reg] + br);
      float z = sigmoidf_(acc_z[rb][reg] + bz);
      float n = tanhf(acc_n[0][rb][reg] + bnx + r*(acc_n[1][rb][reg] + bnh));
      float hold = h_in_f[hidx];
      float hn = (1.f - z)*n + z*hold;
      h_out_f[hidx]  = hn;
      h_out_bf[hidx] = (bf16)hn;
      // output head dot: reduce over this wave's 16 o-columns (lanes within quad)
      float v = hn * wout;
      v += __shfl_xor(v, 1, 64);
      v += __shfl_xor(v, 2, 64);
      v += __shfl_xor(v, 4, 64);
      v += __shfl_xor(v, 8, 64);
      if (l16 == 0) atomicAdd(&dots[(k*Tdim + tmap)*Bdim + b], v);
    }
  }
}

// ---------------- combine fwd/bwd dots + bias -> fp32 out [air BxT | bed BxT] ------------
__global__ __launch_bounds__(256) void finalize_kernel(const float* __restrict__ dots,
                                const float* __restrict__ fc_out_b, float* __restrict__ out){
  int idx = blockIdx.x*256 + threadIdx.x;  // 0..65535
  int head = idx >> 15;
  int b = (idx >> 6) & 511;
  int t = idx & 63;
  float v = dots[(head*Tdim + t)*Bdim + b] + dots[((head+2)*Tdim + t)*Bdim + b]
          + fc_out_b[head];
  out[idx] = v;
}

extern "C" void kernel_launch(void* const* d_in, const int* in_sizes, int n_in,
                              void* d_out, int out_size, void* d_ws, size_t ws_size,
                              hipStream_t stream){
  (void)in_sizes; (void)n_in; (void)out_size; (void)ws_size;
  const float* data     = (const float*)d_in[0];
  const float* init_h   = (const float*)d_in[1];
  const float* fc_in_W  = (const float*)d_in[2];
  const float* fc_in_b  = (const float*)d_in[3];
  const float* Wih      = (const float*)d_in[4];
  const float* Whh      = (const float*)d_in[5];
  const float* bih      = (const float*)d_in[6];
  const float* bhh      = (const float*)d_in[7];
  const float* fc_out_W = (const float*)d_in[8];
  const float* fc_out_b = (const float*)d_in[9];
  float* out = (float*)d_out;

  char* ws = (char*)d_ws;
  bf16*  x_seq   = (bf16*)ws;                     // [T][K][B][H] bf16 : 134217728 B
  bf16*  dataT   = (bf16*)(ws + 134217728);       // [T][B][F]  bf16 :   4194304 B
  float* h_f0    = (float*)(ws + 138412032);      // [K][B][H]  f32  :   4194304 B
  float* h_f1    = (float*)(ws + 142606336);      //                     4194304 B
  bf16*  h_b0    = (bf16*)(ws + 146800640);       // [K][B][H]  bf16 :   2097152 B
  bf16*  h_b1    = (bf16*)(ws + 148897792);       //                     2097152 B
  float* dots    = (float*)(ws + 150994944);      // [K][T][B]  f32  :    524288 B
  bf16*  Wih_bf  = (bf16*)(ws + 151519232);       // [K][3H][H] bf16 :   6291456 B
  bf16*  Whh_bf  = (bf16*)(ws + 157810688);       //                     6291456 B
  bf16*  fcW_bf  = (bf16*)(ws + 164102144);       // [K][H][F]  bf16 :    262144 B

  const int nW  = NC*3*Hdim*Hdim;   // 3,145,728
  const int nFW = NC*Hdim*Fdim;     //   131,072
  hipLaunchKernelGGL(pack_kernel, dim3(nW/1024),  dim3(256), 0, stream, Wih, Wih_bf, nW);
  hipLaunchKernelGGL(pack_kernel, dim3(nW/1024),  dim3(256), 0, stream, Whh, Whh_bf, nW);
  hipLaunchKernelGGL(pack_kernel, dim3(nFW/1024), dim3(256), 0, stream, fc_in_W, fcW_bf, nFW);
  hipLaunchKernelGGL(init_kernel, dim3(4096), dim3(256), 0, stream, init_h, h_f0, h_b0, dots);
  hipLaunchKernelGGL(transpose_kernel, dim3(512), dim3(256), 0, stream, data, dataT);
  hipLaunchKernelGGL(proj_kernel, dim3(8192), dim3(256), 0, stream, dataT, fcW_bf, fc_in_b, x_seq);
  for (int s = 0; s < 64; ++s){
    const float* hi_f = (s & 1) ? h_f1 : h_f0;
    const bf16*  hi_b = (s & 1) ? h_b1 : h_b0;
    float* ho_f = (s & 1) ? h_f0 : h_f1;
    bf16*  ho_b = (s & 1) ? h_b0 : h_b1;
    hipLaunchKernelGGL(step_kernel, dim3(256), dim3(256), 0, stream,
        x_seq, hi_b, hi_f, ho_b, ho_f, Wih_bf, Whh_bf, bih, bhh, fc_out_W, dots, s);
  }
  hipLaunchKernelGGL(finalize_kernel, dim3(256), dim3(256), 0, stream, dots, fc_out_b, out);
}

// Round 3
// 3562.048 us; speedup vs baseline: 1.0439x; 1.0439x over previous
//
#include <hip/hip_runtime.h>
#include <hip/hip_bf16.h>

typedef __hip_bfloat16 bf16;
typedef __attribute__((ext_vector_type(8))) short short8;   // 8 x bf16 (4 VGPRs)
typedef __attribute__((ext_vector_type(4))) float f32x4;

#define Hdim 512
#define Bdim 512
#define Tdim 64
#define Fdim 64
#define NC   4

// s_waitcnt imm: lgkmcnt=0 only (vmcnt=63 no-wait, expcnt=7 no-wait)
#define WAITCNT_LGKM0 0xC07F

__device__ __forceinline__ float sigmoidf_(float x){ return 1.f/(1.f + __expf(-x)); }

// ---------------- fp32 -> bf16 pack (weights) ----------------
__global__ __launch_bounds__(256) void pack_kernel(const float* __restrict__ src,
                                                   bf16* __restrict__ dst, int n){
  int idx = (blockIdx.x*256 + threadIdx.x)*4;
  if (idx < n){
    float4 v = *(const float4*)(src + idx);
    dst[idx+0] = (bf16)v.x;
    dst[idx+1] = (bf16)v.y;
    dst[idx+2] = (bf16)v.z;
    dst[idx+3] = (bf16)v.w;
  }
}

// ---------------- transpose data [B][F][T] fp32 -> dataT [T][B][F] bf16 ----------------
__global__ __launch_bounds__(256) void transpose_kernel(const float* __restrict__ data,
                                                        bf16* __restrict__ dataT){
  __shared__ bf16 tile[64*65];
  int b = blockIdx.x;
  int tid = threadIdx.x;
  for (int i = 0; i < 16; ++i){
    int idx = tid + i*256;
    int f = idx >> 6, t = idx & 63;
    tile[f*65 + t] = (bf16)data[(b*64 + f)*64 + t];
  }
  __syncthreads();
  for (int i = 0; i < 16; ++i){
    int idx = tid + i*256;
    int t = idx >> 6, f = idx & 63;
    dataT[(t*Bdim + b)*64 + f] = tile[f*65 + t];
  }
}

// ---------------- init h state (fp32 + bf16 shadow), zero dot buffer ----------------
__global__ __launch_bounds__(256) void init_kernel(const float* __restrict__ init_h,
                            float* __restrict__ h_f,
                            bf16* __restrict__ h_bf, float* __restrict__ dots){
  int idx = blockIdx.x*256 + threadIdx.x;          // 0 .. 4*512*512-1
  int src = idx & (Bdim*Hdim - 1);                 // broadcast over k
  float v = init_h[src];
  h_f[idx]  = v;
  h_bf[idx] = (bf16)v;
  if (idx < NC*Tdim*Bdim) dots[idx] = 0.f;
}

// ---------------- input projection: x_seq[s][k][b][h] = relu(dataT[src_t] @ fc_in_W[k]^T + b)
__global__ __launch_bounds__(256) void proj_kernel(const bf16* __restrict__ dataT,
    const bf16* __restrict__ fc_in_W, const float* __restrict__ fc_in_b,
    bf16* __restrict__ x_seq){
  __shared__ short ldsA[64*72];
  __shared__ short ldsW[128*72];
  int blk = blockIdx.x;
  int s  = blk >> 7;
  int k  = (blk >> 5) & 3;
  int bt = (blk >> 2) & 7;
  int on = blk & 3;
  int tid = threadIdx.x;
  int lane = tid & 63, wid = tid >> 6;
  int quad = lane >> 4, l16 = lane & 15;
  int src_t = (k < 2) ? s : (Tdim - 1 - s);

  const short* Ag = (const short*)(dataT + (src_t*Bdim + bt*64)*Fdim);
  #pragma unroll
  for (int i = 0; i < 2; ++i){
    int c = tid + i*256; int r = c >> 3, off = c & 7;
    *(int4*)(&ldsA[r*72 + off*8]) = *(const int4*)(&Ag[r*64 + off*8]);
  }
  const short* Wg = (const short*)(fc_in_W + (k*Hdim + on*128)*Fdim);
  #pragma unroll
  for (int i = 0; i < 4; ++i){
    int c = tid + i*256; int r = c >> 3, off = c & 7;
    *(int4*)(&ldsW[r*72 + off*8]) = *(const int4*)(&Wg[r*64 + off*8]);
  }
  __syncthreads();

  f32x4 acc[2][4];
  #pragma unroll
  for (int nt=0; nt<2; ++nt)
    #pragma unroll
    for (int rb=0; rb<4; ++rb) acc[nt][rb] = (f32x4){0.f,0.f,0.f,0.f};

  #pragma unroll
  for (int kk = 0; kk < 2; ++kk){
    int io = kk*32 + quad*8;
    short8 a[4];
    #pragma unroll
    for (int rb=0; rb<4; ++rb) a[rb] = *(const short8*)(&ldsA[(rb*16+l16)*72 + io]);
    #pragma unroll
    for (int nt=0; nt<2; ++nt){
      short8 bw = *(const short8*)(&ldsW[(wid*32 + nt*16 + l16)*72 + io]);
      #pragma unroll
      for (int rb=0; rb<4; ++rb)
        acc[nt][rb] = __builtin_amdgcn_mfma_f32_16x16x32_bf16(a[rb], bw, acc[nt][rb], 0,0,0);
    }
  }

  #pragma unroll
  for (int nt=0; nt<2; ++nt){
    int o = on*128 + wid*32 + nt*16 + l16;
    float bias = fc_in_b[k*Hdim + o];
    #pragma unroll
    for (int rb=0; rb<4; ++rb){
      #pragma unroll
      for (int reg=0; reg<4; ++reg){
        int b = bt*64 + rb*16 + quad*4 + reg;
        float v = acc[nt][rb][reg] + bias;
        v = v > 0.f ? v : 0.f;
        x_seq[((size_t)(s*NC + k)*Bdim + b)*Hdim + o] = (bf16)v;
      }
    }
  }
}

// ---------------- one GRU time step, all 4 cells, software-pipelined staging
// grid 256 = bt(8) x k(4) x ot(8), blk = bt*32 + k*8 + ot  -> XCD = ot (weight L2 pinning).
// K-loop: 16 chunks (2 sides x 8); reg-buffered global loads + double-buffered LDS,
// raw s_barrier + lgkm-only waitcnt so prefetches stay in flight across the barrier.
__global__ __launch_bounds__(256) void step_kernel(
    const bf16* __restrict__ x_seq,
    const bf16* __restrict__ h_in_bf, const float* __restrict__ h_in_f,
    bf16* __restrict__ h_out_bf, float* __restrict__ h_out_f,
    const bf16* __restrict__ Wih, const bf16* __restrict__ Whh,
    const float* __restrict__ bih, const float* __restrict__ bhh,
    const float* __restrict__ fc_out_W,
    float* __restrict__ dots, int s)
{
  __shared__ short ldsIn[2][64*64];      //  16 KB
  __shared__ short ldsW[2][3][64*64];    //  48 KB  (total 64 KB)

  int blk = blockIdx.x;
  int ot = blk & 7;
  int k  = (blk >> 3) & 3;
  int bt = blk >> 5;
  int tid = threadIdx.x;
  int lane = tid & 63, wid = tid >> 6;
  int quad = lane >> 4, l16 = lane & 15;

  // staging address components (same for every chunk)
  int r0 = tid >> 3,        off0 = (tid & 7)*8;
  int r1 = (tid >> 3) + 32, off1 = off0;

  const short* x_base = (const short*)(x_seq + ((size_t)(s*NC + k)*Bdim + bt*64)*Hdim);
  const short* h_base = (const short*)(h_in_bf + (size_t)(k*Bdim + bt*64)*Hdim);
  const short* wi_base = (const short*)(Wih + (size_t)(k*3*Hdim + ot*64)*Hdim);
  const short* wh_base = (const short*)(Whh + (size_t)(k*3*Hdim + ot*64)*Hdim);

  f32x4 acc_r[4], acc_z[4], acc_n[2][4];
  #pragma unroll
  for (int rb=0;rb<4;++rb){
    acc_r[rb]=(f32x4){0.f,0.f,0.f,0.f}; acc_z[rb]=(f32x4){0.f,0.f,0.f,0.f};
    acc_n[0][rb]=(f32x4){0.f,0.f,0.f,0.f}; acc_n[1][rb]=(f32x4){0.f,0.f,0.f,0.f};
  }

  int4 rin[2], rw[6];

  // ---- GLOAD(chunk c): global -> regs ----
  #define GLOAD(c) do {                                                        \
    int side_ = (c) >> 3;  int ib_ = ((c) & 7)*64;                             \
    const short* gi_ = side_ ? h_base : x_base;                                \
    const short* gw_ = side_ ? wh_base : wi_base;                              \
    rin[0] = *(const int4*)(&gi_[r0*Hdim + ib_ + off0]);                       \
    rin[1] = *(const int4*)(&gi_[r1*Hdim + ib_ + off1]);                       \
    _Pragma("unroll")                                                          \
    for (int p_ = 0; p_ < 3; ++p_){                                            \
      rw[p_*2+0] = *(const int4*)(&gw_[(size_t)(p_*Hdim + r0)*Hdim + ib_ + off0]); \
      rw[p_*2+1] = *(const int4*)(&gw_[(size_t)(p_*Hdim + r1)*Hdim + ib_ + off1]); \
    }                                                                          \
  } while(0)

  // ---- DSW(dstbuf): regs -> LDS ----
  #define DSW(d) do {                                                          \
    *(int4*)(&ldsIn[d][r0*64 + off0]) = rin[0];                                \
    *(int4*)(&ldsIn[d][r1*64 + off1]) = rin[1];                                \
    _Pragma("unroll")                                                          \
    for (int p_ = 0; p_ < 3; ++p_){                                            \
      *(int4*)(&ldsW[d][p_][r0*64 + off0]) = rw[p_*2+0];                       \
      *(int4*)(&ldsW[d][p_][r1*64 + off1]) = rw[p_*2+1];                       \
    }                                                                          \
  } while(0)

  // prologue: stage chunk 0, prefetch chunk 1
  GLOAD(0);
  DSW(0);
  GLOAD(1);

  for (int i = 0; i < 16; ++i){
    int buf = i & 1;
    int nacc = i >> 3;   // 0: x-side, 1: h-side (for the n gate)
    // wait own LDS ops (writes of buf, reads of buf^1) WITHOUT draining vmcnt,
    // then raw barrier (no implicit vmcnt(0) drain -> prefetch stays in flight)
    __builtin_amdgcn_s_waitcnt(WAITCNT_LGKM0);
    __builtin_amdgcn_s_barrier();

    #pragma unroll
    for (int kk = 0; kk < 2; ++kk){
      int io = kk*32 + quad*8;
      short8 brf = *(const short8*)(&ldsW[buf][0][(wid*16 + l16)*64 + io]);
      short8 bzf = *(const short8*)(&ldsW[buf][1][(wid*16 + l16)*64 + io]);
      short8 bnf = *(const short8*)(&ldsW[buf][2][(wid*16 + l16)*64 + io]);
      #pragma unroll
      for (int rb = 0; rb < 4; ++rb){
        short8 a = *(const short8*)(&ldsIn[buf][(rb*16 + l16)*64 + io]);
        acc_r[rb] = __builtin_amdgcn_mfma_f32_16x16x32_bf16(a, brf, acc_r[rb], 0,0,0);
        acc_z[rb] = __builtin_amdgcn_mfma_f32_16x16x32_bf16(a, bzf, acc_z[rb], 0,0,0);
        acc_n[nacc][rb] = __builtin_amdgcn_mfma_f32_16x16x32_bf16(a, bnf, acc_n[nacc][rb], 0,0,0);
      }
    }

    if (i < 15){
      DSW(buf ^ 1);          // compiler inserts precise vmcnt wait here (post-MFMA)
      if (i < 14) GLOAD(i + 2);
    }
  }
  #undef GLOAD
  #undef DSW

  int o = ot*64 + wid*16 + l16;
  float br  = bih[k*3*Hdim + o] + bhh[k*3*Hdim + o];
  float bz  = bih[k*3*Hdim + Hdim + o] + bhh[k*3*Hdim + Hdim + o];
  float bnx = bih[k*3*Hdim + 2*Hdim + o];
  float bnh = bhh[k*3*Hdim + 2*Hdim + o];
  float wout = fc_out_W[(k & 1)*Hdim + o];
  int tmap = (k < 2) ? s : (Tdim - 1 - s);

  #pragma unroll
  for (int rb = 0; rb < 4; ++rb){
    #pragma unroll
    for (int reg = 0; reg < 4; ++reg){
      int b = bt*64 + rb*16 + quad*4 + reg;
      size_t hidx = (size_t)(k*Bdim + b)*Hdim + o;
      float r = sigmoidf_(acc_r[rb][reg] + br);
      float z = sigmoidf_(acc_z[rb][reg] + bz);
      float n = tanhf(acc_n[0][rb][reg] + bnx + r*(acc_n[1][rb][reg] + bnh));
      float hold = h_in_f[hidx];
      float hn = (1.f - z)*n + z*hold;
      h_out_f[hidx]  = hn;
      h_out_bf[hidx] = (bf16)hn;
      float v = hn * wout;
      v += __shfl_xor(v, 1, 64);
      v += __shfl_xor(v, 2, 64);
      v += __shfl_xor(v, 4, 64);
      v += __shfl_xor(v, 8, 64);
      if (l16 == 0) atomicAdd(&dots[(k*Tdim + tmap)*Bdim + b], v);
    }
  }
}

// ---------------- combine fwd/bwd dots + bias -> fp32 out [air BxT | bed BxT] ------------
__global__ __launch_bounds__(256) void finalize_kernel(const float* __restrict__ dots,
                                const float* __restrict__ fc_out_b, float* __restrict__ out){
  int idx = blockIdx.x*256 + threadIdx.x;  // 0..65535
  int head = idx >> 15;
  int b = (idx >> 6) & 511;
  int t = idx & 63;
  float v = dots[(head*Tdim + t)*Bdim + b] + dots[((head+2)*Tdim + t)*Bdim + b]
          + fc_out_b[head];
  out[idx] = v;
}

extern "C" void kernel_launch(void* const* d_in, const int* in_sizes, int n_in,
                              void* d_out, int out_size, void* d_ws, size_t ws_size,
                              hipStream_t stream){
  (void)in_sizes; (void)n_in; (void)out_size; (void)ws_size;
  const float* data     = (const float*)d_in[0];
  const float* init_h   = (const float*)d_in[1];
  const float* fc_in_W  = (const float*)d_in[2];
  const float* fc_in_b  = (const float*)d_in[3];
  const float* Wih      = (const float*)d_in[4];
  const float* Whh      = (const float*)d_in[5];
  const float* bih      = (const float*)d_in[6];
  const float* bhh      = (const float*)d_in[7];
  const float* fc_out_W = (const float*)d_in[8];
  const float* fc_out_b = (const float*)d_in[9];
  float* out = (float*)d_out;

  char* ws = (char*)d_ws;
  bf16*  x_seq   = (bf16*)ws;                     // [T][K][B][H] bf16 : 134217728 B
  bf16*  dataT   = (bf16*)(ws + 134217728);       // [T][B][F]  bf16 :   4194304 B
  float* h_f0    = (float*)(ws + 138412032);      // [K][B][H]  f32  :   4194304 B
  float* h_f1    = (float*)(ws + 142606336);      //                     4194304 B
  bf16*  h_b0    = (bf16*)(ws + 146800640);       // [K][B][H]  bf16 :   2097152 B
  bf16*  h_b1    = (bf16*)(ws + 148897792);       //                     2097152 B
  float* dots    = (float*)(ws + 150994944);      // [K][T][B]  f32  :    524288 B
  bf16*  Wih_bf  = (bf16*)(ws + 151519232);       // [K][3H][H] bf16 :   6291456 B
  bf16*  Whh_bf  = (bf16*)(ws + 157810688);       //                     6291456 B
  bf16*  fcW_bf  = (bf16*)(ws + 164102144);       // [K][H][F]  bf16 :    262144 B

  const int nW  = NC*3*Hdim*Hdim;   // 3,145,728
  const int nFW = NC*Hdim*Fdim;     //   131,072
  hipLaunchKernelGGL(pack_kernel, dim3(nW/1024),  dim3(256), 0, stream, Wih, Wih_bf, nW);
  hipLaunchKernelGGL(pack_kernel, dim3(nW/1024),  dim3(256), 0, stream, Whh, Whh_bf, nW);
  hipLaunchKernelGGL(pack_kernel, dim3(nFW/1024), dim3(256), 0, stream, fc_in_W, fcW_bf, nFW);
  hipLaunchKernelGGL(init_kernel, dim3(4096), dim3(256), 0, stream, init_h, h_f0, h_b0, dots);
  hipLaunchKernelGGL(transpose_kernel, dim3(512), dim3(256), 0, stream, data, dataT);
  hipLaunchKernelGGL(proj_kernel, dim3(8192), dim3(256), 0, stream, dataT, fcW_bf, fc_in_b, x_seq);
  for (int s = 0; s < 64; ++s){
    const float* hi_f = (s & 1) ? h_f1 : h_f0;
    const bf16*  hi_b = (s & 1) ? h_b1 : h_b0;
    float* ho_f = (s & 1) ? h_f0 : h_f1;
    bf16*  ho_b = (s & 1) ? h_b0 : h_b1;
    hipLaunchKernelGGL(step_kernel, dim3(256), dim3(256), 0, stream,
        x_seq, hi_b, hi_f, ho_b, ho_f, Wih_bf, Whh_bf, bih, bhh, fc_out_W, dots, s);
  }
  hipLaunchKernelGGL(finalize_kernel, dim3(256), dim3(256), 0, stream, dots, fc_out_b, out);
}

// Round 4
// 3271.919 us; speedup vs baseline: 1.1364x; 1.0887x over previous
//
#include <hip/hip_runtime.h>
#include <hip/hip_bf16.h>

typedef __hip_bfloat16 bf16;
typedef __attribute__((ext_vector_type(8))) short short8;   // 8 x bf16 (4 VGPRs)
typedef __attribute__((ext_vector_type(4))) float f32x4;

#define Hdim 512
#define Bdim 512
#define Tdim 64
#define Fdim 64
#define NC   4

__device__ __forceinline__ float sigmoidf_(float x){ return 1.f/(1.f + __expf(-x)); }

// ---------------- fp32 -> bf16 pack (weights) ----------------
__global__ __launch_bounds__(256) void pack_kernel(const float* __restrict__ src,
                                                   bf16* __restrict__ dst, int n){
  int idx = (blockIdx.x*256 + threadIdx.x)*4;
  if (idx < n){
    float4 v = *(const float4*)(src + idx);
    dst[idx+0] = (bf16)v.x;
    dst[idx+1] = (bf16)v.y;
    dst[idx+2] = (bf16)v.z;
    dst[idx+3] = (bf16)v.w;
  }
}

// ---------------- transpose data [B][F][T] fp32 -> dataT [T][B][F] bf16 ----------------
__global__ __launch_bounds__(256) void transpose_kernel(const float* __restrict__ data,
                                                        bf16* __restrict__ dataT){
  __shared__ bf16 tile[64*65];
  int b = blockIdx.x;
  int tid = threadIdx.x;
  for (int i = 0; i < 16; ++i){
    int idx = tid + i*256;
    int f = idx >> 6, t = idx & 63;
    tile[f*65 + t] = (bf16)data[(b*64 + f)*64 + t];
  }
  __syncthreads();
  for (int i = 0; i < 16; ++i){
    int idx = tid + i*256;
    int t = idx >> 6, f = idx & 63;
    dataT[(t*Bdim + b)*64 + f] = tile[f*65 + t];
  }
}

// ---------------- init: h bf16 shadow broadcast over k, zero dots + barrier counters ----
__global__ __launch_bounds__(256) void init_kernel(const float* __restrict__ init_h,
                            bf16* __restrict__ h_bf, float* __restrict__ dots,
                            unsigned* __restrict__ cnts){
  int idx = blockIdx.x*256 + threadIdx.x;          // 0 .. 4*512*512-1
  int src = idx & (Bdim*Hdim - 1);                 // broadcast over k
  h_bf[idx] = (bf16)init_h[src];
  if (idx < NC*Tdim*Bdim) dots[idx] = 0.f;
  if (idx < 576) cnts[idx] = 0u;                   // lcnt[8][64] + gcnt[64]
}

// ---------------- input projection: x_seq[s][k][b][h] = relu(dataT[src_t] @ fc_in_W[k]^T + b)
__global__ __launch_bounds__(256) void proj_kernel(const bf16* __restrict__ dataT,
    const bf16* __restrict__ fc_in_W, const float* __restrict__ fc_in_b,
    bf16* __restrict__ x_seq){
  __shared__ short ldsA[64*72];
  __shared__ short ldsW[128*72];
  int blk = blockIdx.x;
  int s  = blk >> 7;
  int k  = (blk >> 5) & 3;
  int bt = (blk >> 2) & 7;
  int on = blk & 3;
  int tid = threadIdx.x;
  int lane = tid & 63, wid = tid >> 6;
  int quad = lane >> 4, l16 = lane & 15;
  int src_t = (k < 2) ? s : (Tdim - 1 - s);

  const short* Ag = (const short*)(dataT + (src_t*Bdim + bt*64)*Fdim);
  #pragma unroll
  for (int i = 0; i < 2; ++i){
    int c = tid + i*256; int r = c >> 3, off = c & 7;
    *(int4*)(&ldsA[r*72 + off*8]) = *(const int4*)(&Ag[r*64 + off*8]);
  }
  const short* Wg = (const short*)(fc_in_W + (k*Hdim + on*128)*Fdim);
  #pragma unroll
  for (int i = 0; i < 4; ++i){
    int c = tid + i*256; int r = c >> 3, off = c & 7;
    *(int4*)(&ldsW[r*72 + off*8]) = *(const int4*)(&Wg[r*64 + off*8]);
  }
  __syncthreads();

  f32x4 acc[2][4];
  #pragma unroll
  for (int nt=0; nt<2; ++nt)
    #pragma unroll
    for (int rb=0; rb<4; ++rb) acc[nt][rb] = (f32x4){0.f,0.f,0.f,0.f};

  #pragma unroll
  for (int kk = 0; kk < 2; ++kk){
    int io = kk*32 + quad*8;
    short8 a[4];
    #pragma unroll
    for (int rb=0; rb<4; ++rb) a[rb] = *(const short8*)(&ldsA[(rb*16+l16)*72 + io]);
    #pragma unroll
    for (int nt=0; nt<2; ++nt){
      short8 bw = *(const short8*)(&ldsW[(wid*32 + nt*16 + l16)*72 + io]);
      #pragma unroll
      for (int rb=0; rb<4; ++rb)
        acc[nt][rb] = __builtin_amdgcn_mfma_f32_16x16x32_bf16(a[rb], bw, acc[nt][rb], 0,0,0);
    }
  }

  #pragma unroll
  for (int nt=0; nt<2; ++nt){
    int o = on*128 + wid*32 + nt*16 + l16;
    float bias = fc_in_b[k*Hdim + o];
    #pragma unroll
    for (int rb=0; rb<4; ++rb){
      #pragma unroll
      for (int reg=0; reg<4; ++reg){
        int b = bt*64 + rb*16 + quad*4 + reg;
        float v = acc[nt][rb][reg] + bias;
        v = v > 0.f ? v : 0.f;
        x_seq[((size_t)(s*NC + k)*Bdim + b)*Hdim + o] = (bf16)v;
      }
    }
  }
}

// ---------------- persistent GRU: all 64 steps in one kernel ----------------
// grid 256 = ot(32) x [k(4) x bt(2)]; blk = ot*8 + k*2 + bt  -> XCD group = k*2+bt.
// Each block: o-slice 16 (weights 99.8 KB LDS, loaded once), b-slice 256 (4 waves x 64).
// A-operands (x_seq, h_bf) read directly from global (each element once per block,
// XCD-local in L2). fp32 h state lives in registers. One 2-level grid barrier per step.
__global__ __launch_bounds__(256) void rnn_kernel(
    const bf16* __restrict__ x_seq, const float* __restrict__ init_h,
    bf16* __restrict__ h_b0, bf16* __restrict__ h_b1,
    const bf16* __restrict__ Wih, const bf16* __restrict__ Whh,
    const float* __restrict__ bih, const float* __restrict__ bhh,
    const float* __restrict__ fc_out_W,
    float* __restrict__ dots, unsigned* __restrict__ lcnt, unsigned* __restrict__ gcnt)
{
  __shared__ short wlds[6*16*520];   // 99,840 B: planes {Wih r,z,n, Whh r,z,n}[16 o][512 K+pad]

  int blk = blockIdx.x;
  int ot  = blk >> 3;
  int k   = (blk >> 1) & 3;
  int bt  = blk & 1;
  int grp = blk & 7;
  int tid = threadIdx.x;
  int lane = tid & 63, wid = tid >> 6;
  int quad = lane >> 4, l16 = lane & 15;

  // ---- weights -> LDS, once. plane p: p<3 => Wih gate p ; else Whh gate p-3 ----
  for (int i = tid; i < 6*16*64; i += 256){
    int plane = i >> 10;
    int pos   = i & 1023;
    int row   = pos >> 6;
    int chk   = pos & 63;
    const bf16* wsrc = (plane < 3) ? Wih : Whh;
    int gate = (plane < 3) ? plane : plane - 3;
    const short* src = (const short*)(wsrc + ((size_t)k*3*Hdim + gate*Hdim + ot*16 + row)*Hdim);
    *(int4*)(&wlds[plane*(16*520) + row*520 + chk*8]) = *(const int4*)(&src[chk*8]);
  }

  // per-lane invariants (o-column of this lane)
  int o = ot*16 + l16;
  float br  = bih[k*3*Hdim + o] + bhh[k*3*Hdim + o];
  float bz  = bih[k*3*Hdim + Hdim + o] + bhh[k*3*Hdim + Hdim + o];
  float bnx = bih[k*3*Hdim + 2*Hdim + o];
  float bnh = bhh[k*3*Hdim + 2*Hdim + o];
  float wout = fc_out_W[(k & 1)*Hdim + o];

  // fp32 h state in registers: hk[rb][reg] <-> b = bt*256 + wid*64 + rb*16 + quad*4 + reg
  float hk[4][4];
  #pragma unroll
  for (int rb=0; rb<4; ++rb)
    #pragma unroll
    for (int reg=0; reg<4; ++reg)
      hk[rb][reg] = init_h[(bt*256 + wid*64 + rb*16 + quad*4 + reg)*Hdim + o];

  __syncthreads();

  for (int s = 0; s < 64; ++s){
    const bf16* h_in  = (s & 1) ? h_b1 : h_b0;
    bf16*       h_out = (s & 1) ? h_b0 : h_b1;
    const short* x_base = (const short*)(x_seq + ((size_t)(s*NC + k)*Bdim + bt*256)*Hdim);
    const short* h_base = (const short*)(h_in + (size_t)(k*Bdim + bt*256)*Hdim);

    const short* ar[2][4];
    #pragma unroll
    for (int rb=0; rb<4; ++rb){
      int row = wid*64 + rb*16 + l16;
      ar[0][rb] = x_base + row*Hdim + quad*8;
      ar[1][rb] = h_base + row*Hdim + quad*8;
    }

    f32x4 acc_r[4], acc_z[4], acc_n[2][4];
    #pragma unroll
    for (int rb=0; rb<4; ++rb){
      acc_r[rb]=(f32x4){0.f,0.f,0.f,0.f}; acc_z[rb]=(f32x4){0.f,0.f,0.f,0.f};
      acc_n[0][rb]=(f32x4){0.f,0.f,0.f,0.f}; acc_n[1][rb]=(f32x4){0.f,0.f,0.f,0.f};
    }

    // chunks cc = 0..31: side = cc>>4 (0:x/Wih, 1:h/Whh), kc = cc&15 (K32 slice)
    short8 abuf[3][4];   // depth-2 A prefetch
    short8 bbuf[2][3];   // depth-1 B prefetch
    #pragma unroll
    for (int rb=0; rb<4; ++rb) abuf[0][rb] = *(const short8*)(ar[0][rb]);
    #pragma unroll
    for (int rb=0; rb<4; ++rb) abuf[1][rb] = *(const short8*)(ar[0][rb] + 32);
    #pragma unroll
    for (int g=0; g<3; ++g)
      bbuf[0][g] = *(const short8*)(&wlds[g*(16*520) + l16*520 + quad*8]);

    #pragma unroll
    for (int cc=0; cc<32; ++cc){
      if (cc < 30){
        int nc = cc + 2; int ns = nc >> 4; int nk = nc & 15;
        #pragma unroll
        for (int rb=0; rb<4; ++rb)
          abuf[(cc+2)%3][rb] = *(const short8*)(ar[ns][rb] + nk*32);
      }
      if (cc < 31){
        int nc = cc + 1; int ns = nc >> 4; int nk = nc & 15;
        #pragma unroll
        for (int g=0; g<3; ++g)
          bbuf[(cc+1)&1][g] =
            *(const short8*)(&wlds[(ns*3+g)*(16*520) + l16*520 + nk*32 + quad*8]);
      }
      int nacc = cc >> 4;
      #pragma unroll
      for (int rb=0; rb<4; ++rb){
        short8 a = abuf[cc%3][rb];
        acc_r[rb] = __builtin_amdgcn_mfma_f32_16x16x32_bf16(a, bbuf[cc&1][0], acc_r[rb], 0,0,0);
        acc_z[rb] = __builtin_amdgcn_mfma_f32_16x16x32_bf16(a, bbuf[cc&1][1], acc_z[rb], 0,0,0);
        acc_n[nacc][rb] = __builtin_amdgcn_mfma_f32_16x16x32_bf16(a, bbuf[cc&1][2], acc_n[nacc][rb], 0,0,0);
      }
    }

    // ---- epilogue: gates, h update (registers), bf16 shadow store, output dot ----
    int tmap = (k < 2) ? s : (Tdim - 1 - s);
    #pragma unroll
    for (int rb = 0; rb < 4; ++rb){
      #pragma unroll
      for (int reg = 0; reg < 4; ++reg){
        int b = bt*256 + wid*64 + rb*16 + quad*4 + reg;
        float r = sigmoidf_(acc_r[rb][reg] + br);
        float z = sigmoidf_(acc_z[rb][reg] + bz);
        float n = tanhf(acc_n[0][rb][reg] + bnx + r*(acc_n[1][rb][reg] + bnh));
        float hn = (1.f - z)*n + z*hk[rb][reg];
        hk[rb][reg] = hn;
        h_out[(size_t)(k*Bdim + b)*Hdim + o] = (bf16)hn;
        float v = hn * wout;
        v += __shfl_xor(v, 1, 64);
        v += __shfl_xor(v, 2, 64);
        v += __shfl_xor(v, 4, 64);
        v += __shfl_xor(v, 8, 64);
        if (l16 == 0) atomicAdd(&dots[(k*Tdim + tmap)*Bdim + b], v);
      }
    }

    // ---- 2-level grid barrier (skip after last step) ----
    if (s < 63){
      __threadfence();
      __syncthreads();
      if (tid == 0){
        if (__hip_atomic_fetch_add(&lcnt[grp*64 + s], 1u,
              __ATOMIC_ACQ_REL, __HIP_MEMORY_SCOPE_AGENT) == 31u)
          __hip_atomic_fetch_add(&gcnt[s], 1u,
              __ATOMIC_ACQ_REL, __HIP_MEMORY_SCOPE_AGENT);
        int guard = 0;
        while (__hip_atomic_load(&gcnt[s], __ATOMIC_ACQUIRE, __HIP_MEMORY_SCOPE_AGENT) < 8u){
          __builtin_amdgcn_s_sleep(8);
          if (++guard > 20000000) break;   // ~seconds: never hit unless deadlock
        }
      }
      __syncthreads();
    }
  }
}

// ---------------- combine fwd/bwd dots + bias -> fp32 out [air BxT | bed BxT] ------------
__global__ __launch_bounds__(256) void finalize_kernel(const float* __restrict__ dots,
                                const float* __restrict__ fc_out_b, float* __restrict__ out){
  int idx = blockIdx.x*256 + threadIdx.x;  // 0..65535
  int head = idx >> 15;
  int b = (idx >> 6) & 511;
  int t = idx & 63;
  float v = dots[(head*Tdim + t)*Bdim + b] + dots[((head+2)*Tdim + t)*Bdim + b]
          + fc_out_b[head];
  out[idx] = v;
}

extern "C" void kernel_launch(void* const* d_in, const int* in_sizes, int n_in,
                              void* d_out, int out_size, void* d_ws, size_t ws_size,
                              hipStream_t stream){
  (void)in_sizes; (void)n_in; (void)out_size; (void)ws_size;
  const float* data     = (const float*)d_in[0];
  const float* init_h   = (const float*)d_in[1];
  const float* fc_in_W  = (const float*)d_in[2];
  const float* fc_in_b  = (const float*)d_in[3];
  const float* Wih      = (const float*)d_in[4];
  const float* Whh      = (const float*)d_in[5];
  const float* bih      = (const float*)d_in[6];
  const float* bhh      = (const float*)d_in[7];
  const float* fc_out_W = (const float*)d_in[8];
  const float* fc_out_b = (const float*)d_in[9];
  float* out = (float*)d_out;

  char* ws = (char*)d_ws;
  bf16*  x_seq   = (bf16*)ws;                     // [T][K][B][H] bf16 : 134217728 B
  bf16*  dataT   = (bf16*)(ws + 134217728);       // [T][B][F]  bf16 :   4194304 B
  bf16*  h_b0    = (bf16*)(ws + 138412032);       // [K][B][H]  bf16 :   2097152 B
  bf16*  h_b1    = (bf16*)(ws + 140509184);       //                     2097152 B
  float* dots    = (float*)(ws + 142606336);      // [K][T][B]  f32  :    524288 B
  bf16*  Wih_bf  = (bf16*)(ws + 143130624);       // [K][3H][H] bf16 :   6291456 B
  bf16*  Whh_bf  = (bf16*)(ws + 149422080);       //                     6291456 B
  bf16*  fcW_bf  = (bf16*)(ws + 155713536);       // [K][H][F]  bf16 :    262144 B
  unsigned* lcnt = (unsigned*)(ws + 155975680);   // [8][64] u32 :          2048 B
  unsigned* gcnt = (unsigned*)(ws + 155977728);   // [64] u32    :           256 B

  const int nW  = NC*3*Hdim*Hdim;   // 3,145,728
  const int nFW = NC*Hdim*Fdim;     //   131,072
  hipLaunchKernelGGL(pack_kernel, dim3(nW/1024),  dim3(256), 0, stream, Wih, Wih_bf, nW);
  hipLaunchKernelGGL(pack_kernel, dim3(nW/1024),  dim3(256), 0, stream, Whh, Whh_bf, nW);
  hipLaunchKernelGGL(pack_kernel, dim3(nFW/1024), dim3(256), 0, stream, fc_in_W, fcW_bf, nFW);
  hipLaunchKernelGGL(init_kernel, dim3(4096), dim3(256), 0, stream, init_h, h_b0, dots, lcnt);
  hipLaunchKernelGGL(transpose_kernel, dim3(512), dim3(256), 0, stream, data, dataT);
  hipLaunchKernelGGL(proj_kernel, dim3(8192), dim3(256), 0, stream, dataT, fcW_bf, fc_in_b, x_seq);
  hipLaunchKernelGGL(rnn_kernel, dim3(256), dim3(256), 0, stream,
      x_seq, init_h, h_b0, h_b1, Wih_bf, Whh_bf, bih, bhh, fc_out_W, dots, lcnt, gcnt);
  hipLaunchKernelGGL(finalize_kernel, dim3(256), dim3(256), 0, stream, dots, fc_out_b, out);
}

// Round 5
// 2254.884 us; speedup vs baseline: 1.6490x; 1.4510x over previous
//
#include <hip/hip_runtime.h>
#include <hip/hip_bf16.h>

typedef __hip_bfloat16 bf16;
typedef __attribute__((ext_vector_type(8))) short short8;   // 8 x bf16 (4 VGPRs)
typedef __attribute__((ext_vector_type(4))) float f32x4;

#define Hdim 512
#define Bdim 512
#define Tdim 64
#define Fdim 64
#define NC   4

#define WAITCNT_VM0 0x0F70   // vmcnt(0), expcnt(7), lgkmcnt(15)

__device__ __forceinline__ float sigmoidf_(float x){ return 1.f/(1.f + __expf(-x)); }

// ---------------- fp32 -> bf16 pack (weights) ----------------
__global__ __launch_bounds__(256) void pack_kernel(const float* __restrict__ src,
                                                   bf16* __restrict__ dst, int n){
  int idx = (blockIdx.x*256 + threadIdx.x)*4;
  if (idx < n){
    float4 v = *(const float4*)(src + idx);
    dst[idx+0] = (bf16)v.x;
    dst[idx+1] = (bf16)v.y;
    dst[idx+2] = (bf16)v.z;
    dst[idx+3] = (bf16)v.w;
  }
}

// ---------------- transpose data [B][F][T] fp32 -> dataT [T][B][F] bf16 ----------------
__global__ __launch_bounds__(256) void transpose_kernel(const float* __restrict__ data,
                                                        bf16* __restrict__ dataT){
  __shared__ bf16 tile[64*65];
  int b = blockIdx.x;
  int tid = threadIdx.x;
  for (int i = 0; i < 16; ++i){
    int idx = tid + i*256;
    int f = idx >> 6, t = idx & 63;
    tile[f*65 + t] = (bf16)data[(b*64 + f)*64 + t];
  }
  __syncthreads();
  for (int i = 0; i < 16; ++i){
    int idx = tid + i*256;
    int t = idx >> 6, f = idx & 63;
    dataT[(t*Bdim + b)*64 + f] = tile[f*65 + t];
  }
}

// ---------------- init: h(-1) bf16 shadow (broadcast over k) into h_b1; zero flags ----
__global__ __launch_bounds__(256) void init_kernel(const float* __restrict__ init_h,
                            bf16* __restrict__ h_b1, unsigned* __restrict__ lcnt){
  int idx = blockIdx.x*256 + threadIdx.x;          // 0 .. 4*512*512-1
  int src = idx & (Bdim*Hdim - 1);                 // broadcast over k
  h_b1[idx] = (bf16)init_h[src];
  if (idx < 512) lcnt[idx] = 0u;                   // lcnt[8][64]
}

// ---------------- input projection: x_seq[s][k][b][h] = relu(dataT[src_t] @ fc_in_W[k]^T + b)
__global__ __launch_bounds__(256) void proj_kernel(const bf16* __restrict__ dataT,
    const bf16* __restrict__ fc_in_W, const float* __restrict__ fc_in_b,
    bf16* __restrict__ x_seq){
  __shared__ short ldsA[64*72];
  __shared__ short ldsW[128*72];
  int blk = blockIdx.x;
  int s  = blk >> 7;
  int k  = (blk >> 5) & 3;
  int bt = (blk >> 2) & 7;
  int on = blk & 3;
  int tid = threadIdx.x;
  int lane = tid & 63, wid = tid >> 6;
  int quad = lane >> 4, l16 = lane & 15;
  int src_t = (k < 2) ? s : (Tdim - 1 - s);

  const short* Ag = (const short*)(dataT + (src_t*Bdim + bt*64)*Fdim);
  #pragma unroll
  for (int i = 0; i < 2; ++i){
    int c = tid + i*256; int r = c >> 3, off = c & 7;
    *(int4*)(&ldsA[r*72 + off*8]) = *(const int4*)(&Ag[r*64 + off*8]);
  }
  const short* Wg = (const short*)(fc_in_W + (k*Hdim + on*128)*Fdim);
  #pragma unroll
  for (int i = 0; i < 4; ++i){
    int c = tid + i*256; int r = c >> 3, off = c & 7;
    *(int4*)(&ldsW[r*72 + off*8]) = *(const int4*)(&Wg[r*64 + off*8]);
  }
  __syncthreads();

  f32x4 acc[2][4];
  #pragma unroll
  for (int nt=0; nt<2; ++nt)
    #pragma unroll
    for (int rb=0; rb<4; ++rb) acc[nt][rb] = (f32x4){0.f,0.f,0.f,0.f};

  #pragma unroll
  for (int kk = 0; kk < 2; ++kk){
    int io = kk*32 + quad*8;
    short8 a[4];
    #pragma unroll
    for (int rb=0; rb<4; ++rb) a[rb] = *(const short8*)(&ldsA[(rb*16+l16)*72 + io]);
    #pragma unroll
    for (int nt=0; nt<2; ++nt){
      short8 bw = *(const short8*)(&ldsW[(wid*32 + nt*16 + l16)*72 + io]);
      #pragma unroll
      for (int rb=0; rb<4; ++rb)
        acc[nt][rb] = __builtin_amdgcn_mfma_f32_16x16x32_bf16(a[rb], bw, acc[nt][rb], 0,0,0);
    }
  }

  #pragma unroll
  for (int nt=0; nt<2; ++nt){
    int o = on*128 + wid*32 + nt*16 + l16;
    float bias = fc_in_b[k*Hdim + o];
    #pragma unroll
    for (int rb=0; rb<4; ++rb){
      #pragma unroll
      for (int reg=0; reg<4; ++reg){
        int b = bt*64 + rb*16 + quad*4 + reg;
        float v = acc[nt][rb][reg] + bias;
        v = v > 0.f ? v : 0.f;
        x_seq[((size_t)(s*NC + k)*Bdim + b)*Hdim + o] = (bf16)v;
      }
    }
  }
}

// ---------------- persistent GRU: all 64 steps in one kernel ----------------
// grid 256 = ot(32) x [k(4) x bt(2)]; blk = ot*8 + k*2 + bt; grp = k*2+bt = XCD.
// Dependency graph is block-diagonal over the 8 (k,bt) groups -> per-group barrier only.
// Per step: x-side GEMM (no dependency) -> wait group flag(s-1) -> h-side GEMM ->
// epilogue -> vmcnt drain -> signal flag(s). Weights in LDS, fragment-swizzled
// (lane-contiguous 16B reads -> conflict-free). fp32 h state in registers.
__global__ __launch_bounds__(256) void rnn_kernel(
    const bf16* __restrict__ x_seq, const float* __restrict__ init_h,
    bf16* __restrict__ h_b0, bf16* __restrict__ h_b1,
    const bf16* __restrict__ Wih, const bf16* __restrict__ Whh,
    const float* __restrict__ bih, const float* __restrict__ bhh,
    const float* __restrict__ fc_out_W,
    float* __restrict__ part, unsigned* __restrict__ lcnt)
{
  __shared__ short wlds[6*16*64*8];   // 96 KB: [plane(6)][kc(16)][lane(64)] x 8 bf16 frags

  int blk = blockIdx.x;
  int ot  = blk >> 3;
  int k   = (blk >> 1) & 3;
  int bt  = blk & 1;
  int grp = blk & 7;
  int tid = threadIdx.x;
  int lane = tid & 63, wid = tid >> 6;
  int quad = lane >> 4, l16 = lane & 15;

  // ---- weights -> LDS once, in B-fragment lane order.
  // plane p<3: Wih gate p ; p>=3: Whh gate p-3. frag(lane=(quad<<4)|l16, kc):
  // W[o = ot*16 + l16][kc*32 + quad*8 .. +8]
  for (int i = tid; i < 6*16*64; i += 256){
    int plane = i >> 10;
    int rem   = i & 1023;
    int kc    = rem >> 6;
    int ln    = rem & 63;
    int ll16  = ln & 15, lq = ln >> 4;
    const bf16* wsrc = (plane < 3) ? Wih : Whh;
    int gate = (plane < 3) ? plane : plane - 3;
    const short* src = (const short*)(wsrc +
        ((size_t)(k*3 + gate)*Hdim + ot*16 + ll16)*Hdim + kc*32 + lq*8);
    *(int4*)(&wlds[i*8]) = *(const int4*)src;
  }

  int o = ot*16 + l16;
  float br  = bih[k*3*Hdim + o] + bhh[k*3*Hdim + o];
  float bz  = bih[k*3*Hdim + Hdim + o] + bhh[k*3*Hdim + Hdim + o];
  float bnx = bih[k*3*Hdim + 2*Hdim + o];
  float bnh = bhh[k*3*Hdim + 2*Hdim + o];
  float wout = fc_out_W[(k & 1)*Hdim + o];

  // fp32 h state in registers: hk[rb][reg] <-> b = bt*256 + wid*64 + rb*16 + quad*4 + reg
  float hk[4][4];
  #pragma unroll
  for (int rb=0; rb<4; ++rb)
    #pragma unroll
    for (int reg=0; reg<4; ++reg)
      hk[rb][reg] = init_h[(bt*256 + wid*64 + rb*16 + quad*4 + reg)*Hdim + o];

  __syncthreads();

  // one GEMM side: 16 K32 chunks, depth-4 A prefetch from global, depth-1 B from LDS
  #define GEMM_SIDE(SIDE, ABASE, NACC) do {                                     \
    const short* ap_[4];                                                        \
    _Pragma("unroll")                                                           \
    for (int rb=0; rb<4; ++rb)                                                  \
      ap_[rb] = (ABASE) + (wid*64 + rb*16 + l16)*Hdim + quad*8;                 \
    short8 ab_[4][4];                                                           \
    _Pragma("unroll")                                                           \
    for (int d=0; d<4; ++d)                                                     \
      _Pragma("unroll")                                                         \
      for (int rb=0; rb<4; ++rb) ab_[d][rb] = *(const short8*)(ap_[rb] + d*32); \
    short8 bb_[2][3];                                                           \
    _Pragma("unroll")                                                           \
    for (int g=0; g<3; ++g)                                                     \
      bb_[0][g] = *(const short8*)(&wlds[((((SIDE)*3+g)*16 + 0)<<9) + (lane<<3)]); \
    _Pragma("unroll")                                                           \
    for (int kc=0; kc<16; ++kc){                                                \
      short8 acur_[4];                                                          \
      _Pragma("unroll")                                                         \
      for (int rb=0; rb<4; ++rb) acur_[rb] = ab_[kc&3][rb];                     \
      if (kc < 12){                                                             \
        _Pragma("unroll")                                                       \
        for (int rb=0; rb<4; ++rb)                                              \
          ab_[kc&3][rb] = *(const short8*)(ap_[rb] + (kc+4)*32);                \
      }                                                                         \
      if (kc < 15){                                                             \
        _Pragma("unroll")                                                       \
        for (int g=0; g<3; ++g)                                                 \
          bb_[(kc+1)&1][g] =                                                    \
            *(const short8*)(&wlds[((((SIDE)*3+g)*16 + kc+1)<<9) + (lane<<3)]); \
      }                                                                         \
      _Pragma("unroll")                                                         \
      for (int rb=0; rb<4; ++rb){                                               \
        acc_r[rb] = __builtin_amdgcn_mfma_f32_16x16x32_bf16(acur_[rb], bb_[kc&1][0], acc_r[rb], 0,0,0); \
        acc_z[rb] = __builtin_amdgcn_mfma_f32_16x16x32_bf16(acur_[rb], bb_[kc&1][1], acc_z[rb], 0,0,0); \
        acc_n[NACC][rb] = __builtin_amdgcn_mfma_f32_16x16x32_bf16(acur_[rb], bb_[kc&1][2], acc_n[NACC][rb], 0,0,0); \
      }                                                                         \
    }                                                                           \
  } while(0)

  for (int s = 0; s < 64; ++s){
    const bf16* h_in  = (s & 1) ? h_b0 : h_b1;   // H[s-1] lives in buf[(s-1)&1]
    bf16*       h_out = (s & 1) ? h_b1 : h_b0;   // H[s]   goes to buf[s&1]

    f32x4 acc_r[4], acc_z[4], acc_n[2][4];
    #pragma unroll
    for (int rb=0; rb<4; ++rb){
      acc_r[rb]=(f32x4){0.f,0.f,0.f,0.f}; acc_z[rb]=(f32x4){0.f,0.f,0.f,0.f};
      acc_n[0][rb]=(f32x4){0.f,0.f,0.f,0.f}; acc_n[1][rb]=(f32x4){0.f,0.f,0.f,0.f};
    }

    // ---- x-side (independent of other blocks) ----
    const short* x_base = (const short*)(x_seq + ((size_t)(s*NC + k)*Bdim + bt*256)*Hdim);
    GEMM_SIDE(0, x_base, 0);

    // ---- wait for group's h(s-1) (hidden behind the x-side compute above) ----
    if (s){
      if (tid == 0){
        int guard = 0;
        while (__hip_atomic_load(&lcnt[grp*64 + s-1], __ATOMIC_ACQUIRE,
                                 __HIP_MEMORY_SCOPE_AGENT) < 32u){
          __builtin_amdgcn_s_sleep(1);
          if (++guard > 50000000) break;
        }
      }
      __syncthreads();
      __builtin_amdgcn_fence(__ATOMIC_ACQUIRE, "agent");
    }

    // ---- h-side ----
    const short* h_base = (const short*)(h_in + (size_t)(k*Bdim + bt*256)*Hdim);
    GEMM_SIDE(1, h_base, 1);

    // ---- epilogue: gates, register h update, bf16 shadow store, partial dot ----
    int tmap = (k < 2) ? s : (Tdim - 1 - s);
    #pragma unroll
    for (int rb = 0; rb < 4; ++rb){
      #pragma unroll
      for (int reg = 0; reg < 4; ++reg){
        int b = bt*256 + wid*64 + rb*16 + quad*4 + reg;
        float r = sigmoidf_(acc_r[rb][reg] + br);
        float z = sigmoidf_(acc_z[rb][reg] + bz);
        float n = tanhf(acc_n[0][rb][reg] + bnx + r*(acc_n[1][rb][reg] + bnh));
        float hn = (1.f - z)*n + z*hk[rb][reg];
        hk[rb][reg] = hn;
        h_out[(size_t)(k*Bdim + b)*Hdim + o] = (bf16)hn;
        float v = hn * wout;
        v += __shfl_xor(v, 1, 64);
        v += __shfl_xor(v, 2, 64);
        v += __shfl_xor(v, 4, 64);
        v += __shfl_xor(v, 8, 64);
        if (l16 == 0) part[((k*Tdim + tmap)*Bdim + b)*32 + ot] = v;
      }
    }

    // ---- signal: h(s) visible in (XCD-local) L2, then arrive ----
    if (s < 63){
      __builtin_amdgcn_s_waitcnt(WAITCNT_VM0);   // own stores drained to L2
      __syncthreads();                            // all waves drained
      if (tid == 0)
        __hip_atomic_fetch_add(&lcnt[grp*64 + s], 1u,
                               __ATOMIC_RELEASE, __HIP_MEMORY_SCOPE_AGENT);
    }
  }
  #undef GEMM_SIDE
}

// ---------------- out[head][b][t] = bias + sum over {head,head+2} x 32 ot-partials ----
__global__ __launch_bounds__(256) void finalize_kernel(const float* __restrict__ part,
                                const float* __restrict__ fc_out_b, float* __restrict__ out){
  int idx = blockIdx.x*256 + threadIdx.x;  // 0..65535
  int head = idx >> 15;
  int b = (idx >> 6) & 511;
  int t = idx & 63;
  float v = fc_out_b[head];
  #pragma unroll
  for (int kk = 0; kk < 2; ++kk){
    const float* p = part + (((head + kk*2)*Tdim + t)*Bdim + b)*32;
    #pragma unroll
    for (int j = 0; j < 8; ++j){
      float4 f = *(const float4*)(p + j*4);
      v += f.x + f.y + f.z + f.w;
    }
  }
  out[idx] = v;
}

extern "C" void kernel_launch(void* const* d_in, const int* in_sizes, int n_in,
                              void* d_out, int out_size, void* d_ws, size_t ws_size,
                              hipStream_t stream){
  (void)in_sizes; (void)n_in; (void)out_size; (void)ws_size;
  const float* data     = (const float*)d_in[0];
  const float* init_h   = (const float*)d_in[1];
  const float* fc_in_W  = (const float*)d_in[2];
  const float* fc_in_b  = (const float*)d_in[3];
  const float* Wih      = (const float*)d_in[4];
  const float* Whh      = (const float*)d_in[5];
  const float* bih      = (const float*)d_in[6];
  const float* bhh      = (const float*)d_in[7];
  const float* fc_out_W = (const float*)d_in[8];
  const float* fc_out_b = (const float*)d_in[9];
  float* out = (float*)d_out;

  char* ws = (char*)d_ws;
  bf16*  x_seq   = (bf16*)ws;                     // [T][K][B][H] bf16 : 134217728 B
  bf16*  h_b0    = (bf16*)(ws + 134217728);       // [K][B][H]  bf16 :   2097152 B
  bf16*  h_b1    = (bf16*)(ws + 136314880);       //                     2097152 B
  float* part    = (float*)(ws + 138412032);      // [K][T][B][32] f32:  16777216 B
  bf16*  dataT   = (bf16*)(ws + 138412032);       // overlay (dead before rnn): 4 MB
  bf16*  fcW_bf  = (bf16*)(ws + 142606336);       // overlay (dead before rnn): 256 KB
  bf16*  Wih_bf  = (bf16*)(ws + 155189248);       // [K][3H][H] bf16 :   6291456 B
  bf16*  Whh_bf  = (bf16*)(ws + 161480704);       //                     6291456 B
  unsigned* lcnt = (unsigned*)(ws + 167772160);   // [8][64] u32 :          2048 B

  const int nW  = NC*3*Hdim*Hdim;   // 3,145,728
  const int nFW = NC*Hdim*Fdim;     //   131,072
  hipLaunchKernelGGL(pack_kernel, dim3(nW/1024),  dim3(256), 0, stream, Wih, Wih_bf, nW);
  hipLaunchKernelGGL(pack_kernel, dim3(nW/1024),  dim3(256), 0, stream, Whh, Whh_bf, nW);
  hipLaunchKernelGGL(pack_kernel, dim3(nFW/1024), dim3(256), 0, stream, fc_in_W, fcW_bf, nFW);
  hipLaunchKernelGGL(init_kernel, dim3(4096), dim3(256), 0, stream, init_h, h_b1, lcnt);
  hipLaunchKernelGGL(transpose_kernel, dim3(512), dim3(256), 0, stream, data, dataT);
  hipLaunchKernelGGL(proj_kernel, dim3(8192), dim3(256), 0, stream, dataT, fcW_bf, fc_in_b, x_seq);
  hipLaunchKernelGGL(rnn_kernel, dim3(256), dim3(256), 0, stream,
      x_seq, init_h, h_b0, h_b1, Wih_bf, Whh_bf, bih, bhh, fc_out_W, part, lcnt);
  hipLaunchKernelGGL(finalize_kernel, dim3(256), dim3(256), 0, stream, part, fc_out_b, out);
}

// Round 6
// 1431.251 us; speedup vs baseline: 2.5980x; 1.5755x over previous
//
#include <hip/hip_runtime.h>
#include <hip/hip_bf16.h>

typedef __hip_bfloat16 bf16;
typedef __attribute__((ext_vector_type(8))) short short8;   // 8 x bf16 (4 VGPRs)
typedef __attribute__((ext_vector_type(4))) float f32x4;

#define Hdim 512
#define Bdim 512
#define Tdim 64
#define Fdim 64
#define NC   4

__device__ __forceinline__ float sigmoidf_(float x){ return 1.f/(1.f + __expf(-x)); }

// ---------------- fp32 -> bf16 pack (weights) ----------------
__global__ __launch_bounds__(256) void pack_kernel(const float* __restrict__ src,
                                                   bf16* __restrict__ dst, int n){
  int idx = (blockIdx.x*256 + threadIdx.x)*4;
  if (idx < n){
    float4 v = *(const float4*)(src + idx);
    dst[idx+0] = (bf16)v.x;
    dst[idx+1] = (bf16)v.y;
    dst[idx+2] = (bf16)v.z;
    dst[idx+3] = (bf16)v.w;
  }
}

// ---------------- transpose data [B][F][T] fp32 -> dataT [T][B][F] bf16 ----------------
__global__ __launch_bounds__(256) void transpose_kernel(const float* __restrict__ data,
                                                        bf16* __restrict__ dataT){
  __shared__ bf16 tile[64*65];
  int b = blockIdx.x;
  int tid = threadIdx.x;
  for (int i = 0; i < 16; ++i){
    int idx = tid + i*256;
    int f = idx >> 6, t = idx & 63;
    tile[f*65 + t] = (bf16)data[(b*64 + f)*64 + t];
  }
  __syncthreads();
  for (int i = 0; i < 16; ++i){
    int idx = tid + i*256;
    int t = idx >> 6, f = idx & 63;
    dataT[(t*Bdim + b)*64 + f] = tile[f*65 + t];
  }
}

// ---------------- init: h(-1) bf16 shadow (broadcast over k) into h_b1; zero flags ----
__global__ __launch_bounds__(256) void init_kernel(const float* __restrict__ init_h,
                            bf16* __restrict__ h_b1, unsigned* __restrict__ flags){
  int idx = blockIdx.x*256 + threadIdx.x;          // 0 .. 4*512*512-1
  int src = idx & (Bdim*Hdim - 1);                 // broadcast over k
  h_b1[idx] = (bf16)init_h[src];
  if (idx < 512) flags[idx] = 0u;                  // flags[8][32] + xslot[8][32-pad]
}

// ---------------- input projection: x_seq[s][k][b][h] = relu(dataT[src_t] @ fc_in_W[k]^T + b)
__global__ __launch_bounds__(256) void proj_kernel(const bf16* __restrict__ dataT,
    const bf16* __restrict__ fc_in_W, const float* __restrict__ fc_in_b,
    bf16* __restrict__ x_seq){
  __shared__ short ldsA[64*72];
  __shared__ short ldsW[128*72];
  int blk = blockIdx.x;
  int s  = blk >> 7;
  int k  = (blk >> 5) & 3;
  int bt = (blk >> 2) & 7;
  int on = blk & 3;
  int tid = threadIdx.x;
  int lane = tid & 63, wid = tid >> 6;
  int quad = lane >> 4, l16 = lane & 15;
  int src_t = (k < 2) ? s : (Tdim - 1 - s);

  const short* Ag = (const short*)(dataT + (src_t*Bdim + bt*64)*Fdim);
  #pragma unroll
  for (int i = 0; i < 2; ++i){
    int c = tid + i*256; int r = c >> 3, off = c & 7;
    *(int4*)(&ldsA[r*72 + off*8]) = *(const int4*)(&Ag[r*64 + off*8]);
  }
  const short* Wg = (const short*)(fc_in_W + (k*Hdim + on*128)*Fdim);
  #pragma unroll
  for (int i = 0; i < 4; ++i){
    int c = tid + i*256; int r = c >> 3, off = c & 7;
    *(int4*)(&ldsW[r*72 + off*8]) = *(const int4*)(&Wg[r*64 + off*8]);
  }
  __syncthreads();

  f32x4 acc[2][4];
  #pragma unroll
  for (int nt=0; nt<2; ++nt)
    #pragma unroll
    for (int rb=0; rb<4; ++rb) acc[nt][rb] = (f32x4){0.f,0.f,0.f,0.f};

  #pragma unroll
  for (int kk = 0; kk < 2; ++kk){
    int io = kk*32 + quad*8;
    short8 a[4];
    #pragma unroll
    for (int rb=0; rb<4; ++rb) a[rb] = *(const short8*)(&ldsA[(rb*16+l16)*72 + io]);
    #pragma unroll
    for (int nt=0; nt<2; ++nt){
      short8 bw = *(const short8*)(&ldsW[(wid*32 + nt*16 + l16)*72 + io]);
      #pragma unroll
      for (int rb=0; rb<4; ++rb)
        acc[nt][rb] = __builtin_amdgcn_mfma_f32_16x16x32_bf16(a[rb], bw, acc[nt][rb], 0,0,0);
    }
  }

  #pragma unroll
  for (int nt=0; nt<2; ++nt){
    int o = on*128 + wid*32 + nt*16 + l16;
    float bias = fc_in_b[k*Hdim + o];
    #pragma unroll
    for (int rb=0; rb<4; ++rb){
      #pragma unroll
      for (int reg=0; reg<4; ++reg){
        int b = bt*64 + rb*16 + quad*4 + reg;
        float v = acc[nt][rb][reg] + bias;
        v = v > 0.f ? v : 0.f;
        x_seq[((size_t)(s*NC + k)*Bdim + b)*Hdim + o] = (bf16)v;
      }
    }
  }
}

// ---------------- persistent GRU: all 64 steps in one kernel ----------------
// Blocks SELF-ASSIGN to dependency groups by physical XCD (s_getreg XCC_ID + local
// slot grab) -> each group's 32 blocks share one L2, which is then the coherence
// point: relaxed workgroup-scope atomics (local L2, no sc1, no invalidates) +
// __syncthreads (drains vmcnt) give producer->consumer ordering with ZERO fences.
// Per block: o-slice 16 (96 KB swizzled weight LDS), b-slice 256; fp32 h in regs.
// Per step: x-side GEMM -> poll 32 per-block flags (one 32-lane atomic) -> h-side
// GEMM -> epilogue -> syncthreads -> bump own flag.
__global__ __launch_bounds__(256) void rnn_kernel(
    const bf16* __restrict__ x_seq, const float* __restrict__ init_h,
    bf16* __restrict__ h_b0, bf16* __restrict__ h_b1,
    const bf16* __restrict__ Wih, const bf16* __restrict__ Whh,
    const float* __restrict__ bih, const float* __restrict__ bhh,
    const float* __restrict__ fc_out_W,
    float* __restrict__ part, unsigned* __restrict__ flags, unsigned* __restrict__ xslot)
{
  __shared__ short wlds[6*16*64*8];   // 96 KB: [plane(6)][kc(16)][lane(64)] x 8 bf16 frags
  __shared__ int sslot;

  int tid = threadIdx.x;
  int lane = tid & 63, wid = tid >> 6;
  int quad = lane >> 4, l16 = lane & 15;

  // ---- physical-XCD self-assignment ----
  unsigned xcc;
  asm volatile("s_getreg_b32 %0, hwreg(HW_REG_XCC_ID)" : "=s"(xcc));
  xcc &= 7u;
  if (tid == 0)
    sslot = (int)__hip_atomic_fetch_add(&xslot[xcc*32], 1u,
                __ATOMIC_RELAXED, __HIP_MEMORY_SCOPE_WORKGROUP);
  __syncthreads();
  int grp = (int)xcc;          // dependency group == physical XCD
  int k   = grp >> 1;
  int bt  = grp & 1;
  int ot  = sslot & 31;        // 0..31 unique within the XCD (pigeonhole: 1 block/CU)
  unsigned* gflags = flags + grp*32;   // 32 u32 = one 128B line, exclusive to this XCD

  // ---- weights -> LDS once, in B-fragment lane order ----
  for (int i = tid; i < 6*16*64; i += 256){
    int plane = i >> 10;
    int rem   = i & 1023;
    int kc    = rem >> 6;
    int ln    = rem & 63;
    int ll16  = ln & 15, lq = ln >> 4;
    const bf16* wsrc = (plane < 3) ? Wih : Whh;
    int gate = (plane < 3) ? plane : plane - 3;
    const short* src = (const short*)(wsrc +
        ((size_t)(k*3 + gate)*Hdim + ot*16 + ll16)*Hdim + kc*32 + lq*8);
    *(int4*)(&wlds[i*8]) = *(const int4*)src;
  }

  int o = ot*16 + l16;
  float br  = bih[k*3*Hdim + o] + bhh[k*3*Hdim + o];
  float bz  = bih[k*3*Hdim + Hdim + o] + bhh[k*3*Hdim + Hdim + o];
  float bnx = bih[k*3*Hdim + 2*Hdim + o];
  float bnh = bhh[k*3*Hdim + 2*Hdim + o];
  float wout = fc_out_W[(k & 1)*Hdim + o];

  // fp32 h state in registers: hk[rb][reg] <-> b = bt*256 + wid*64 + rb*16 + quad*4 + reg
  float hk[4][4];
  #pragma unroll
  for (int rb=0; rb<4; ++rb)
    #pragma unroll
    for (int reg=0; reg<4; ++reg)
      hk[rb][reg] = init_h[(bt*256 + wid*64 + rb*16 + quad*4 + reg)*Hdim + o];

  __syncthreads();

  // one GEMM side: 16 K32 chunks, depth-4 A prefetch from global, depth-1 B from LDS
  #define GEMM_SIDE(SIDE, ABASE, NACC) do {                                     \
    const short* ap_[4];                                                        \
    _Pragma("unroll")                                                           \
    for (int rb=0; rb<4; ++rb)                                                  \
      ap_[rb] = (ABASE) + (wid*64 + rb*16 + l16)*Hdim + quad*8;                 \
    short8 ab_[4][4];                                                           \
    _Pragma("unroll")                                                           \
    for (int d=0; d<4; ++d)                                                     \
      _Pragma("unroll")                                                         \
      for (int rb=0; rb<4; ++rb) ab_[d][rb] = *(const short8*)(ap_[rb] + d*32); \
    short8 bb_[2][3];                                                           \
    _Pragma("unroll")                                                           \
    for (int g=0; g<3; ++g)                                                     \
      bb_[0][g] = *(const short8*)(&wlds[((((SIDE)*3+g)*16 + 0)<<9) + (lane<<3)]); \
    _Pragma("unroll")                                                           \
    for (int kc=0; kc<16; ++kc){                                                \
      short8 acur_[4];                                                          \
      _Pragma("unroll")                                                         \
      for (int rb=0; rb<4; ++rb) acur_[rb] = ab_[kc&3][rb];                     \
      if (kc < 12){                                                             \
        _Pragma("unroll")                                                       \
        for (int rb=0; rb<4; ++rb)                                              \
          ab_[kc&3][rb] = *(const short8*)(ap_[rb] + (kc+4)*32);                \
      }                                                                         \
      if (kc < 15){                                                             \
        _Pragma("unroll")                                                       \
        for (int g=0; g<3; ++g)                                                 \
          bb_[(kc+1)&1][g] =                                                    \
            *(const short8*)(&wlds[((((SIDE)*3+g)*16 + kc+1)<<9) + (lane<<3)]); \
      }                                                                         \
      _Pragma("unroll")                                                         \
      for (int rb=0; rb<4; ++rb){                                               \
        acc_r[rb] = __builtin_amdgcn_mfma_f32_16x16x32_bf16(acur_[rb], bb_[kc&1][0], acc_r[rb], 0,0,0); \
        acc_z[rb] = __builtin_amdgcn_mfma_f32_16x16x32_bf16(acur_[rb], bb_[kc&1][1], acc_z[rb], 0,0,0); \
        acc_n[NACC][rb] = __builtin_amdgcn_mfma_f32_16x16x32_bf16(acur_[rb], bb_[kc&1][2], acc_n[NACC][rb], 0,0,0); \
      }                                                                         \
    }                                                                           \
  } while(0)

  for (int s = 0; s < 64; ++s){
    const bf16* h_in  = (s & 1) ? h_b0 : h_b1;   // H[s-1] lives in buf[(s-1)&1]
    bf16*       h_out = (s & 1) ? h_b1 : h_b0;   // H[s]   goes to buf[s&1]

    f32x4 acc_r[4], acc_z[4], acc_n[2][4];
    #pragma unroll
    for (int rb=0; rb<4; ++rb){
      acc_r[rb]=(f32x4){0.f,0.f,0.f,0.f}; acc_z[rb]=(f32x4){0.f,0.f,0.f,0.f};
      acc_n[0][rb]=(f32x4){0.f,0.f,0.f,0.f}; acc_n[1][rb]=(f32x4){0.f,0.f,0.f,0.f};
    }

    // ---- x-side (independent of other blocks) ----
    const short* x_base = (const short*)(x_seq + ((size_t)(s*NC + k)*Bdim + bt*256)*Hdim);
    GEMM_SIDE(0, x_base, 0);

    // ---- wait: all 32 group flags >= s. One 32-lane local-L2 atomic per poll. ----
    if (s){
      if (wid == 0){
        int guard = 0;
        for (;;){
          unsigned v = __hip_atomic_fetch_add(&gflags[lane & 31], 0u,
                          __ATOMIC_RELAXED, __HIP_MEMORY_SCOPE_WORKGROUP);
          if (__ballot(v >= (unsigned)s) == ~0ull) break;
          __builtin_amdgcn_s_sleep(2);
          if (++guard > 1000000) break;
        }
      }
      __syncthreads();   // also the compiler memory barrier for the h loads below
    }

    // ---- h-side ----
    const short* h_base = (const short*)(h_in + (size_t)(k*Bdim + bt*256)*Hdim);
    GEMM_SIDE(1, h_base, 1);

    // ---- epilogue: gates, register h update, bf16 shadow store, partial dot ----
    int tmap = (k < 2) ? s : (Tdim - 1 - s);
    #pragma unroll
    for (int rb = 0; rb < 4; ++rb){
      #pragma unroll
      for (int reg = 0; reg < 4; ++reg){
        int b = bt*256 + wid*64 + rb*16 + quad*4 + reg;
        float r = sigmoidf_(acc_r[rb][reg] + br);
        float z = sigmoidf_(acc_z[rb][reg] + bz);
        float n = tanhf(acc_n[0][rb][reg] + bnx + r*(acc_n[1][rb][reg] + bnh));
        float hn = (1.f - z)*n + z*hk[rb][reg];
        hk[rb][reg] = hn;
        h_out[(size_t)(k*Bdim + b)*Hdim + o] = (bf16)hn;
        float v = hn * wout;
        v += __shfl_xor(v, 1, 64);
        v += __shfl_xor(v, 2, 64);
        v += __shfl_xor(v, 4, 64);
        v += __shfl_xor(v, 8, 64);
        if (l16 == 0) part[((k*Tdim + tmap)*Bdim + b)*32 + ot] = v;
      }
    }

    // ---- signal: __syncthreads drains vmcnt(0) for all waves (h in local L2),
    //      then bump own flag with a local-L2 relaxed atomic ----
    if (s < 63){
      __syncthreads();
      if (tid == 0)
        __hip_atomic_fetch_add(&gflags[ot], 1u,
                               __ATOMIC_RELAXED, __HIP_MEMORY_SCOPE_WORKGROUP);
    }
  }
  #undef GEMM_SIDE
}

// ---------------- out[head][b][t] = bias + sum over {head,head+2} x 32 ot-partials ----
__global__ __launch_bounds__(256) void finalize_kernel(const float* __restrict__ part,
                                const float* __restrict__ fc_out_b, float* __restrict__ out){
  int idx = blockIdx.x*256 + threadIdx.x;  // 0..65535
  int head = idx >> 15;
  int b = (idx >> 6) & 511;
  int t = idx & 63;
  float v = fc_out_b[head];
  #pragma unroll
  for (int kk = 0; kk < 2; ++kk){
    const float* p = part + (((head + kk*2)*Tdim + t)*Bdim + b)*32;
    #pragma unroll
    for (int j = 0; j < 8; ++j){
      float4 f = *(const float4*)(p + j*4);
      v += f.x + f.y + f.z + f.w;
    }
  }
  out[idx] = v;
}

extern "C" void kernel_launch(void* const* d_in, const int* in_sizes, int n_in,
                              void* d_out, int out_size, void* d_ws, size_t ws_size,
                              hipStream_t stream){
  (void)in_sizes; (void)n_in; (void)out_size; (void)ws_size;
  const float* data     = (const float*)d_in[0];
  const float* init_h   = (const float*)d_in[1];
  const float* fc_in_W  = (const float*)d_in[2];
  const float* fc_in_b  = (const float*)d_in[3];
  const float* Wih      = (const float*)d_in[4];
  const float* Whh      = (const float*)d_in[5];
  const float* bih      = (const float*)d_in[6];
  const float* bhh      = (const float*)d_in[7];
  const float* fc_out_W = (const float*)d_in[8];
  const float* fc_out_b = (const float*)d_in[9];
  float* out = (float*)d_out;

  char* ws = (char*)d_ws;
  bf16*  x_seq   = (bf16*)ws;                     // [T][K][B][H] bf16 : 134217728 B
  bf16*  h_b0    = (bf16*)(ws + 134217728);       // [K][B][H]  bf16 :   2097152 B
  bf16*  h_b1    = (bf16*)(ws + 136314880);       //                     2097152 B
  float* part    = (float*)(ws + 138412032);      // [K][T][B][32] f32:  16777216 B
  bf16*  dataT   = (bf16*)(ws + 138412032);       // overlay (dead before rnn): 4 MB
  bf16*  fcW_bf  = (bf16*)(ws + 142606336);       // overlay (dead before rnn): 256 KB
  bf16*  Wih_bf  = (bf16*)(ws + 155189248);       // [K][3H][H] bf16 :   6291456 B
  bf16*  Whh_bf  = (bf16*)(ws + 161480704);       //                     6291456 B
  unsigned* flags= (unsigned*)(ws + 167772160);   // [8][32] u32 = 1024 B (1 line/XCD)
  unsigned* xslot= (unsigned*)(ws + 167773184);   // [8][32] u32 = 1024 B (128B stride)

  const int nW  = NC*3*Hdim*Hdim;   // 3,145,728
  const int nFW = NC*Hdim*Fdim;     //   131,072
  hipLaunchKernelGGL(pack_kernel, dim3(nW/1024),  dim3(256), 0, stream, Wih, Wih_bf, nW);
  hipLaunchKernelGGL(pack_kernel, dim3(nW/1024),  dim3(256), 0, stream, Whh, Whh_bf, nW);
  hipLaunchKernelGGL(pack_kernel, dim3(nFW/1024), dim3(256), 0, stream, fc_in_W, fcW_bf, nFW);
  hipLaunchKernelGGL(init_kernel, dim3(4096), dim3(256), 0, stream, init_h, h_b1, flags);
  hipLaunchKernelGGL(transpose_kernel, dim3(512), dim3(256), 0, stream, data, dataT);
  hipLaunchKernelGGL(proj_kernel, dim3(8192), dim3(256), 0, stream, dataT, fcW_bf, fc_in_b, x_seq);
  hipLaunchKernelGGL(rnn_kernel, dim3(256), dim3(256), 0, stream,
      x_seq, init_h, h_b0, h_b1, Wih_bf, Whh_bf, bih, bhh, fc_out_W, part, flags, xslot);
  hipLaunchKernelGGL(finalize_kernel, dim3(256), dim3(256), 0, stream, part, fc_out_b, out);
}

// Round 7
// 1325.791 us; speedup vs baseline: 2.8046x; 1.0795x over previous
//
#include <hip/hip_runtime.h>
#include <hip/hip_bf16.h>

typedef __hip_bfloat16 bf16;
typedef __attribute__((ext_vector_type(8))) short short8;   // 8 x bf16 (4 VGPRs)
typedef __attribute__((ext_vector_type(4))) float f32x4;

#define Hdim 512
#define Bdim 512
#define Tdim 64
#define Fdim 64
#define NC   4

__device__ __forceinline__ float sigmoidf_(float x){ return 1.f/(1.f + __expf(-x)); }
__device__ __forceinline__ float tanhf_(float x){
  float t = __expf(-2.f*fabsf(x));
  float r = (1.f - t)/(1.f + t);
  return copysignf(r, x);
}

// ---------------- fp32 -> bf16 pack (weights) ----------------
__global__ __launch_bounds__(256) void pack_kernel(const float* __restrict__ src,
                                                   bf16* __restrict__ dst, int n){
  int idx = (blockIdx.x*256 + threadIdx.x)*4;
  if (idx < n){
    float4 v = *(const float4*)(src + idx);
    dst[idx+0] = (bf16)v.x;
    dst[idx+1] = (bf16)v.y;
    dst[idx+2] = (bf16)v.z;
    dst[idx+3] = (bf16)v.w;
  }
}

// ---------------- transpose data [B][F][T] fp32 -> dataT [T][B][F] bf16 ----------------
__global__ __launch_bounds__(256) void transpose_kernel(const float* __restrict__ data,
                                                        bf16* __restrict__ dataT){
  __shared__ bf16 tile[64*65];
  int b = blockIdx.x;
  int tid = threadIdx.x;
  for (int i = 0; i < 16; ++i){
    int idx = tid + i*256;
    int f = idx >> 6, t = idx & 63;
    tile[f*65 + t] = (bf16)data[(b*64 + f)*64 + t];
  }
  __syncthreads();
  for (int i = 0; i < 16; ++i){
    int idx = tid + i*256;
    int t = idx >> 6, f = idx & 63;
    dataT[(t*Bdim + b)*64 + f] = tile[f*65 + t];
  }
}

// ---------------- init: h(-1) bf16 shadow (broadcast over k) into h_b1; zero flags ----
__global__ __launch_bounds__(256) void init_kernel(const float* __restrict__ init_h,
                            bf16* __restrict__ h_b1, unsigned* __restrict__ flags){
  int idx = blockIdx.x*256 + threadIdx.x;          // 0 .. 4*512*512-1
  int src = idx & (Bdim*Hdim - 1);                 // broadcast over k
  h_b1[idx] = (bf16)init_h[src];
  if (idx < 768) flags[idx] = 0u;                  // flags[8][64] + xslot[8][32]
}

// ---------------- input projection: x_seq[s][k][b][h] = relu(dataT[src_t] @ fc_in_W[k]^T + b)
__global__ __launch_bounds__(256) void proj_kernel(const bf16* __restrict__ dataT,
    const bf16* __restrict__ fc_in_W, const float* __restrict__ fc_in_b,
    bf16* __restrict__ x_seq){
  __shared__ short ldsA[64*72];
  __shared__ short ldsW[128*72];
  int blk = blockIdx.x;
  int s  = blk >> 7;
  int k  = (blk >> 5) & 3;
  int bt = (blk >> 2) & 7;
  int on = blk & 3;
  int tid = threadIdx.x;
  int lane = tid & 63, wid = tid >> 6;
  int quad = lane >> 4, l16 = lane & 15;
  int src_t = (k < 2) ? s : (Tdim - 1 - s);

  const short* Ag = (const short*)(dataT + (src_t*Bdim + bt*64)*Fdim);
  #pragma unroll
  for (int i = 0; i < 2; ++i){
    int c = tid + i*256; int r = c >> 3, off = c & 7;
    *(int4*)(&ldsA[r*72 + off*8]) = *(const int4*)(&Ag[r*64 + off*8]);
  }
  const short* Wg = (const short*)(fc_in_W + (k*Hdim + on*128)*Fdim);
  #pragma unroll
  for (int i = 0; i < 4; ++i){
    int c = tid + i*256; int r = c >> 3, off = c & 7;
    *(int4*)(&ldsW[r*72 + off*8]) = *(const int4*)(&Wg[r*64 + off*8]);
  }
  __syncthreads();

  f32x4 acc[2][4];
  #pragma unroll
  for (int nt=0; nt<2; ++nt)
    #pragma unroll
    for (int rb=0; rb<4; ++rb) acc[nt][rb] = (f32x4){0.f,0.f,0.f,0.f};

  #pragma unroll
  for (int kk = 0; kk < 2; ++kk){
    int io = kk*32 + quad*8;
    short8 a[4];
    #pragma unroll
    for (int rb=0; rb<4; ++rb) a[rb] = *(const short8*)(&ldsA[(rb*16+l16)*72 + io]);
    #pragma unroll
    for (int nt=0; nt<2; ++nt){
      short8 bw = *(const short8*)(&ldsW[(wid*32 + nt*16 + l16)*72 + io]);
      #pragma unroll
      for (int rb=0; rb<4; ++rb)
        acc[nt][rb] = __builtin_amdgcn_mfma_f32_16x16x32_bf16(a[rb], bw, acc[nt][rb], 0,0,0);
    }
  }

  #pragma unroll
  for (int nt=0; nt<2; ++nt){
    int o = on*128 + wid*32 + nt*16 + l16;
    float bias = fc_in_b[k*Hdim + o];
    #pragma unroll
    for (int rb=0; rb<4; ++rb){
      #pragma unroll
      for (int reg=0; reg<4; ++reg){
        int b = bt*64 + rb*16 + quad*4 + reg;
        float v = acc[nt][rb][reg] + bias;
        v = v > 0.f ? v : 0.f;
        x_seq[((size_t)(s*NC + k)*Bdim + b)*Hdim + o] = (bf16)v;
      }
    }
  }
}

// ---------------- persistent GRU: all 64 steps in one kernel ----------------
// Blocks self-assign by physical XCD (s_getreg XCC_ID + slot grab) -> each group's
// 32 blocks share one L2 = the coherence point; relaxed workgroup-scope atomics +
// __syncthreads give producer->consumer ordering with zero fences.
// Sync: ONE counter per group (256B-spaced line). Bump = 1 RMW/block/step (tid0);
// poll = single-lane fetch_add(0) until >= 32*s.  (Round-6 32-lane RMW poll on one
// line was the contention hotspot.)
// L2 traffic: 32 blocks/group sweep the same x/h slice -> K-ring PHASE-STAGGERED
// by (ot&15) so blocks start at different chunks (no same-line burst).
__global__ __launch_bounds__(256) void rnn_kernel(
    const bf16* __restrict__ x_seq, const float* __restrict__ init_h,
    bf16* __restrict__ h_b0, bf16* __restrict__ h_b1,
    const bf16* __restrict__ Wih, const bf16* __restrict__ Whh,
    const float* __restrict__ bih, const float* __restrict__ bhh,
    const float* __restrict__ fc_out_W,
    float* __restrict__ part, unsigned* __restrict__ flags, unsigned* __restrict__ xslot)
{
  __shared__ short wlds[6*16*64*8];   // 96 KB: [plane(6)][kc(16)][lane(64)] x 8 bf16 frags
  __shared__ int sslot;

  int tid = threadIdx.x;
  int lane = tid & 63, wid = tid >> 6;
  int quad = lane >> 4, l16 = lane & 15;

  // ---- physical-XCD self-assignment ----
  unsigned xcc;
  asm volatile("s_getreg_b32 %0, hwreg(HW_REG_XCC_ID)" : "=s"(xcc));
  xcc &= 7u;
  if (tid == 0)
    sslot = (int)__hip_atomic_fetch_add(&xslot[xcc*32], 1u,
                __ATOMIC_RELAXED, __HIP_MEMORY_SCOPE_WORKGROUP);
  __syncthreads();
  int grp = (int)xcc;          // dependency group == physical XCD
  int k   = grp >> 1;
  int bt  = grp & 1;
  int ot  = sslot & 31;        // 0..31 unique within the XCD (pigeonhole: 1 block/CU)
  int rot = ot & 15;           // K-ring phase stagger
  unsigned* gflag = flags + grp*64;    // one u32 counter, 256B line exclusive to XCD

  // ---- weights -> LDS once, in B-fragment lane order ----
  for (int i = tid; i < 6*16*64; i += 256){
    int plane = i >> 10;
    int rem   = i & 1023;
    int kc    = rem >> 6;
    int ln    = rem & 63;
    int ll16  = ln & 15, lq = ln >> 4;
    const bf16* wsrc = (plane < 3) ? Wih : Whh;
    int gate = (plane < 3) ? plane : plane - 3;
    const short* src = (const short*)(wsrc +
        ((size_t)(k*3 + gate)*Hdim + ot*16 + ll16)*Hdim + kc*32 + lq*8);
    *(int4*)(&wlds[i*8]) = *(const int4*)src;
  }

  int o = ot*16 + l16;
  float br  = bih[k*3*Hdim + o] + bhh[k*3*Hdim + o];
  float bz  = bih[k*3*Hdim + Hdim + o] + bhh[k*3*Hdim + Hdim + o];
  float bnx = bih[k*3*Hdim + 2*Hdim + o];
  float bnh = bhh[k*3*Hdim + 2*Hdim + o];
  float wout = fc_out_W[(k & 1)*Hdim + o];

  // fp32 h state in registers: hk[rb][reg] <-> b = bt*256 + wid*64 + rb*16 + quad*4 + reg
  float hk[4][4];
  #pragma unroll
  for (int rb=0; rb<4; ++rb)
    #pragma unroll
    for (int reg=0; reg<4; ++reg)
      hk[rb][reg] = init_h[(bt*256 + wid*64 + rb*16 + quad*4 + reg)*Hdim + o];

  __syncthreads();

  // one GEMM side: 16 K32 chunks starting at phase `rot`, depth-4 A prefetch from
  // global, depth-1 B from LDS
  #define GEMM_SIDE(SIDE, ABASE, NACC) do {                                     \
    const short* ap_[4];                                                        \
    _Pragma("unroll")                                                           \
    for (int rb=0; rb<4; ++rb)                                                  \
      ap_[rb] = (ABASE) + (wid*64 + rb*16 + l16)*Hdim + quad*8;                 \
    short8 ab_[4][4];                                                           \
    _Pragma("unroll")                                                           \
    for (int d=0; d<4; ++d)                                                     \
      _Pragma("unroll")                                                         \
      for (int rb=0; rb<4; ++rb)                                                \
        ab_[d][rb] = *(const short8*)(ap_[rb] + ((d + rot) & 15)*32);           \
    short8 bb_[2][3];                                                           \
    _Pragma("unroll")                                                           \
    for (int g=0; g<3; ++g)                                                     \
      bb_[0][g] = *(const short8*)(&wlds[((((SIDE)*3+g)*16 + rot)<<9) + (lane<<3)]); \
    _Pragma("unroll")                                                           \
    for (int kc=0; kc<16; ++kc){                                                \
      short8 acur_[4];                                                          \
      _Pragma("unroll")                                                         \
      for (int rb=0; rb<4; ++rb) acur_[rb] = ab_[kc&3][rb];                     \
      if (kc < 12){                                                             \
        _Pragma("unroll")                                                       \
        for (int rb=0; rb<4; ++rb)                                              \
          ab_[kc&3][rb] = *(const short8*)(ap_[rb] + ((kc + 4 + rot) & 15)*32); \
      }                                                                         \
      if (kc < 15){                                                             \
        _Pragma("unroll")                                                       \
        for (int g=0; g<3; ++g)                                                 \
          bb_[(kc+1)&1][g] =                                                    \
            *(const short8*)(&wlds[((((SIDE)*3+g)*16 + ((kc + 1 + rot) & 15))<<9) + (lane<<3)]); \
      }                                                                         \
      _Pragma("unroll")                                                         \
      for (int rb=0; rb<4; ++rb){                                               \
        acc_r[rb] = __builtin_amdgcn_mfma_f32_16x16x32_bf16(acur_[rb], bb_[kc&1][0], acc_r[rb], 0,0,0); \
        acc_z[rb] = __builtin_amdgcn_mfma_f32_16x16x32_bf16(acur_[rb], bb_[kc&1][1], acc_z[rb], 0,0,0); \
        acc_n[NACC][rb] = __builtin_amdgcn_mfma_f32_16x16x32_bf16(acur_[rb], bb_[kc&1][2], acc_n[NACC][rb], 0,0,0); \
      }                                                                         \
    }                                                                           \
  } while(0)

  for (int s = 0; s < 64; ++s){
    const bf16* h_in  = (s & 1) ? h_b0 : h_b1;   // H[s-1] lives in buf[(s-1)&1]
    bf16*       h_out = (s & 1) ? h_b1 : h_b0;   // H[s]   goes to buf[s&1]

    f32x4 acc_r[4], acc_z[4], acc_n[2][4];
    #pragma unroll
    for (int rb=0; rb<4; ++rb){
      acc_r[rb]=(f32x4){0.f,0.f,0.f,0.f}; acc_z[rb]=(f32x4){0.f,0.f,0.f,0.f};
      acc_n[0][rb]=(f32x4){0.f,0.f,0.f,0.f}; acc_n[1][rb]=(f32x4){0.f,0.f,0.f,0.f};
    }

    // ---- x-side (independent of other blocks; overlaps others' step-(s-1) tail) ----
    const short* x_base = (const short*)(x_seq + ((size_t)(s*NC + k)*Bdim + bt*256)*Hdim);
    GEMM_SIDE(0, x_base, 0);

    // ---- wait: group counter >= 32*s. Single-lane RMW poll (L2-resident line). ----
    if (s){
      if (tid == 0){
        int guard = 0;
        while (__hip_atomic_fetch_add(gflag, 0u,
                  __ATOMIC_RELAXED, __HIP_MEMORY_SCOPE_WORKGROUP) < 32u*(unsigned)s){
          __builtin_amdgcn_s_sleep(2);
          if (++guard > 2000000) break;
        }
      }
      __syncthreads();   // also the compiler memory barrier for the h loads below
    }

    // ---- h-side ----
    const short* h_base = (const short*)(h_in + (size_t)(k*Bdim + bt*256)*Hdim);
    GEMM_SIDE(1, h_base, 1);

    // ---- epilogue: gates, register h update, bf16 shadow store, partial dot ----
    int tmap = (k < 2) ? s : (Tdim - 1 - s);
    #pragma unroll
    for (int rb = 0; rb < 4; ++rb){
      #pragma unroll
      for (int reg = 0; reg < 4; ++reg){
        int b = bt*256 + wid*64 + rb*16 + quad*4 + reg;
        float r = sigmoidf_(acc_r[rb][reg] + br);
        float z = sigmoidf_(acc_z[rb][reg] + bz);
        float n = tanhf_(acc_n[0][rb][reg] + bnx + r*(acc_n[1][rb][reg] + bnh));
        float hn = (1.f - z)*n + z*hk[rb][reg];
        hk[rb][reg] = hn;
        h_out[(size_t)(k*Bdim + b)*Hdim + o] = (bf16)hn;
        float v = hn * wout;
        v += __shfl_xor(v, 1, 64);
        v += __shfl_xor(v, 2, 64);
        v += __shfl_xor(v, 4, 64);
        v += __shfl_xor(v, 8, 64);
        if (l16 == 0) part[((k*Tdim + tmap)*Bdim + b)*32 + ot] = v;
      }
    }

    // ---- signal: __syncthreads drains vmcnt(0) for all waves (h in local L2),
    //      then one relaxed local-L2 RMW bump of the group counter ----
    if (s < 63){
      __syncthreads();
      if (tid == 0)
        __hip_atomic_fetch_add(gflag, 1u,
                               __ATOMIC_RELAXED, __HIP_MEMORY_SCOPE_WORKGROUP);
    }
  }
  #undef GEMM_SIDE
}

// ---------------- out[head][b][t] = bias + sum over {head,head+2} x 32 ot-partials ----
__global__ __launch_bounds__(256) void finalize_kernel(const float* __restrict__ part,
                                const float* __restrict__ fc_out_b, float* __restrict__ out){
  int idx = blockIdx.x*256 + threadIdx.x;  // 0..65535
  int head = idx >> 15;
  int b = (idx >> 6) & 511;
  int t = idx & 63;
  float v = fc_out_b[head];
  #pragma unroll
  for (int kk = 0; kk < 2; ++kk){
    const float* p = part + (((head + kk*2)*Tdim + t)*Bdim + b)*32;
    #pragma unroll
    for (int j = 0; j < 8; ++j){
      float4 f = *(const float4*)(p + j*4);
      v += f.x + f.y + f.z + f.w;
    }
  }
  out[idx] = v;
}

extern "C" void kernel_launch(void* const* d_in, const int* in_sizes, int n_in,
                              void* d_out, int out_size, void* d_ws, size_t ws_size,
                              hipStream_t stream){
  (void)in_sizes; (void)n_in; (void)out_size; (void)ws_size;
  const float* data     = (const float*)d_in[0];
  const float* init_h   = (const float*)d_in[1];
  const float* fc_in_W  = (const float*)d_in[2];
  const float* fc_in_b  = (const float*)d_in[3];
  const float* Wih      = (const float*)d_in[4];
  const float* Whh      = (const float*)d_in[5];
  const float* bih      = (const float*)d_in[6];
  const float* bhh      = (const float*)d_in[7];
  const float* fc_out_W = (const float*)d_in[8];
  const float* fc_out_b = (const float*)d_in[9];
  float* out = (float*)d_out;

  char* ws = (char*)d_ws;
  bf16*  x_seq   = (bf16*)ws;                     // [T][K][B][H] bf16 : 134217728 B
  bf16*  h_b0    = (bf16*)(ws + 134217728);       // [K][B][H]  bf16 :   2097152 B
  bf16*  h_b1    = (bf16*)(ws + 136314880);       //                     2097152 B
  float* part    = (float*)(ws + 138412032);      // [K][T][B][32] f32:  16777216 B
  bf16*  dataT   = (bf16*)(ws + 138412032);       // overlay (dead before rnn): 4 MB
  bf16*  fcW_bf  = (bf16*)(ws + 142606336);       // overlay (dead before rnn): 256 KB
  bf16*  Wih_bf  = (bf16*)(ws + 155189248);       // [K][3H][H] bf16 :   6291456 B
  bf16*  Whh_bf  = (bf16*)(ws + 161480704);       //                     6291456 B
  unsigned* flags= (unsigned*)(ws + 167772160);   // [8][64] u32 = 2048 B (256B line/XCD)
  unsigned* xslot= (unsigned*)(ws + 167774208);   // [8][32] u32 = 1024 B (128B stride)

  const int nW  = NC*3*Hdim*Hdim;   // 3,145,728
  const int nFW = NC*Hdim*Fdim;     //   131,072
  hipLaunchKernelGGL(pack_kernel, dim3(nW/1024),  dim3(256), 0, stream, Wih, Wih_bf, nW);
  hipLaunchKernelGGL(pack_kernel, dim3(nW/1024),  dim3(256), 0, stream, Whh, Whh_bf, nW);
  hipLaunchKernelGGL(pack_kernel, dim3(nFW/1024), dim3(256), 0, stream, fc_in_W, fcW_bf, nFW);
  hipLaunchKernelGGL(init_kernel, dim3(4096), dim3(256), 0, stream, init_h, h_b1, flags);
  hipLaunchKernelGGL(transpose_kernel, dim3(512), dim3(256), 0, stream, data, dataT);
  hipLaunchKernelGGL(proj_kernel, dim3(8192), dim3(256), 0, stream, dataT, fcW_bf, fc_in_b, x_seq);
  hipLaunchKernelGGL(rnn_kernel, dim3(256), dim3(256), 0, stream,
      x_seq, init_h, h_b0, h_b1, Wih_bf, Whh_bf, bih, bhh, fc_out_W, part, flags, xslot);
  hipLaunchKernelGGL(finalize_kernel, dim3(256), dim3(256), 0, stream, part, fc_out_b, out);
}

// Round 8
// 1194.661 us; speedup vs baseline: 3.1125x; 1.1098x over previous
//
#include <hip/hip_runtime.h>
#include <hip/hip_bf16.h>

typedef __hip_bfloat16 bf16;
typedef __attribute__((ext_vector_type(8))) short short8;   // 8 x bf16 (4 VGPRs)
typedef __attribute__((ext_vector_type(4))) float f32x4;

#define Hdim 512
#define Bdim 512
#define Tdim 64
#define Fdim 64
#define NC   4

__device__ __forceinline__ float sigmoidf_(float x){ return 1.f/(1.f + __expf(-x)); }
__device__ __forceinline__ float tanhf_(float x){
  float t = __expf(-2.f*fabsf(x));
  float r = (1.f - t)/(1.f + t);
  return copysignf(r, x);
}

// ---------------- fp32 -> bf16 pack (weights) ----------------
__global__ __launch_bounds__(256) void pack_kernel(const float* __restrict__ src,
                                                   bf16* __restrict__ dst, int n){
  int idx = (blockIdx.x*256 + threadIdx.x)*4;
  if (idx < n){
    float4 v = *(const float4*)(src + idx);
    dst[idx+0] = (bf16)v.x;
    dst[idx+1] = (bf16)v.y;
    dst[idx+2] = (bf16)v.z;
    dst[idx+3] = (bf16)v.w;
  }
}

// ---------------- transpose data [B][F][T] fp32 -> dataT [T][B][F] bf16 ----------------
__global__ __launch_bounds__(256) void transpose_kernel(const float* __restrict__ data,
                                                        bf16* __restrict__ dataT){
  __shared__ bf16 tile[64*65];
  int b = blockIdx.x;
  int tid = threadIdx.x;
  for (int i = 0; i < 16; ++i){
    int idx = tid + i*256;
    int f = idx >> 6, t = idx & 63;
    tile[f*65 + t] = (bf16)data[(b*64 + f)*64 + t];
  }
  __syncthreads();
  for (int i = 0; i < 16; ++i){
    int idx = tid + i*256;
    int t = idx >> 6, f = idx & 63;
    dataT[(t*Bdim + b)*64 + f] = tile[f*65 + t];
  }
}

// ---------------- init: h(-1) bf16 shadow (broadcast over k) into h_b1; zero flags ----
__global__ __launch_bounds__(256) void init_kernel(const float* __restrict__ init_h,
                            bf16* __restrict__ h_b1, unsigned* __restrict__ flags){
  int idx = blockIdx.x*256 + threadIdx.x;          // 0 .. 4*512*512-1
  int src = idx & (Bdim*Hdim - 1);                 // broadcast over k
  h_b1[idx] = (bf16)init_h[src];
  if (idx < 768) flags[idx] = 0u;                  // flags[8][32](+pad) + xslot[8][32]
}

// ---------------- input projection: x_seq[s][k][b][h] = relu(dataT[src_t] @ fc_in_W[k]^T + b)
__global__ __launch_bounds__(256) void proj_kernel(const bf16* __restrict__ dataT,
    const bf16* __restrict__ fc_in_W, const float* __restrict__ fc_in_b,
    bf16* __restrict__ x_seq){
  __shared__ short ldsA[64*72];
  __shared__ short ldsW[128*72];
  int blk = blockIdx.x;
  int s  = blk >> 7;
  int k  = (blk >> 5) & 3;
  int bt = (blk >> 2) & 7;
  int on = blk & 3;
  int tid = threadIdx.x;
  int lane = tid & 63, wid = tid >> 6;
  int quad = lane >> 4, l16 = lane & 15;
  int src_t = (k < 2) ? s : (Tdim - 1 - s);

  const short* Ag = (const short*)(dataT + (src_t*Bdim + bt*64)*Fdim);
  #pragma unroll
  for (int i = 0; i < 2; ++i){
    int c = tid + i*256; int r = c >> 3, off = c & 7;
    *(int4*)(&ldsA[r*72 + off*8]) = *(const int4*)(&Ag[r*64 + off*8]);
  }
  const short* Wg = (const short*)(fc_in_W + (k*Hdim + on*128)*Fdim);
  #pragma unroll
  for (int i = 0; i < 4; ++i){
    int c = tid + i*256; int r = c >> 3, off = c & 7;
    *(int4*)(&ldsW[r*72 + off*8]) = *(const int4*)(&Wg[r*64 + off*8]);
  }
  __syncthreads();

  f32x4 acc[2][4];
  #pragma unroll
  for (int nt=0; nt<2; ++nt)
    #pragma unroll
    for (int rb=0; rb<4; ++rb) acc[nt][rb] = (f32x4){0.f,0.f,0.f,0.f};

  #pragma unroll
  for (int kk = 0; kk < 2; ++kk){
    int io = kk*32 + quad*8;
    short8 a[4];
    #pragma unroll
    for (int rb=0; rb<4; ++rb) a[rb] = *(const short8*)(&ldsA[(rb*16+l16)*72 + io]);
    #pragma unroll
    for (int nt=0; nt<2; ++nt){
      short8 bw = *(const short8*)(&ldsW[(wid*32 + nt*16 + l16)*72 + io]);
      #pragma unroll
      for (int rb=0; rb<4; ++rb)
        acc[nt][rb] = __builtin_amdgcn_mfma_f32_16x16x32_bf16(a[rb], bw, acc[nt][rb], 0,0,0);
    }
  }

  #pragma unroll
  for (int nt=0; nt<2; ++nt){
    int o = on*128 + wid*32 + nt*16 + l16;
    float bias = fc_in_b[k*Hdim + o];
    #pragma unroll
    for (int rb=0; rb<4; ++rb){
      #pragma unroll
      for (int reg=0; reg<4; ++reg){
        int b = bt*64 + rb*16 + quad*4 + reg;
        float v = acc[nt][rb][reg] + bias;
        v = v > 0.f ? v : 0.f;
        x_seq[((size_t)(s*NC + k)*Bdim + b)*Hdim + o] = (bf16)v;
      }
    }
  }
}

// ---------------- persistent GRU: all 64 steps in one kernel ----------------
// Grid 256 x 512 threads (8 waves -> 2 waves/SIMD: round-7's 1 wave/SIMD exposed
// every latency serially; TLP is the fix). Blocks self-assign by physical XCD
// (s_getreg XCC_ID + slot grab) -> each group's 32 blocks share one L2 = the
// coherence point; relaxed atomics + vmcnt-draining __syncthreads give
// producer->consumer ordering with zero fences. Per block: o-slice 16 (96 KB
// swizzled weight LDS, loaded once); per wave: 32 b-rows. fp32 h in registers.
// K-ring phase-staggered by ot to spread L2 bank demand.
__global__ __launch_bounds__(512) void rnn_kernel(
    const bf16* __restrict__ x_seq, const float* __restrict__ init_h,
    bf16* __restrict__ h_b0, bf16* __restrict__ h_b1,
    const bf16* __restrict__ Wih, const bf16* __restrict__ Whh,
    const float* __restrict__ bih, const float* __restrict__ bhh,
    const float* __restrict__ fc_out_W,
    float* __restrict__ part, unsigned* __restrict__ flags, unsigned* __restrict__ xslot)
{
  __shared__ short wlds[6*16*64*8];   // 96 KB: [plane(6)][kc(16)][lane(64)] x 8 bf16 frags
  __shared__ int sslot;

  int tid = threadIdx.x;
  int lane = tid & 63, wid = tid >> 6;          // wid 0..7
  int quad = lane >> 4, l16 = lane & 15;

  // ---- physical-XCD self-assignment ----
  unsigned xcc;
  asm volatile("s_getreg_b32 %0, hwreg(HW_REG_XCC_ID)" : "=s"(xcc));
  xcc &= 7u;
  if (tid == 0)
    sslot = (int)__hip_atomic_fetch_add(&xslot[xcc*32], 1u,
                __ATOMIC_RELAXED, __HIP_MEMORY_SCOPE_WORKGROUP);
  __syncthreads();
  int grp = (int)xcc;          // dependency group == physical XCD
  int k   = grp >> 1;
  int bt  = grp & 1;
  int ot  = sslot & 31;        // 0..31 unique within the XCD (pigeonhole: 1 block/CU)
  int rot = ot & 15;           // K-ring phase stagger
  unsigned* gflags = flags + grp*32;   // 32 per-block counters, one line per XCD

  // ---- weights -> LDS once, in B-fragment lane order ----
  for (int i = tid; i < 6*16*64; i += 512){
    int plane = i >> 10;
    int rem   = i & 1023;
    int kc    = rem >> 6;
    int ln    = rem & 63;
    int ll16  = ln & 15, lq = ln >> 4;
    const bf16* wsrc = (plane < 3) ? Wih : Whh;
    int gate = (plane < 3) ? plane : plane - 3;
    const short* src = (const short*)(wsrc +
        ((size_t)(k*3 + gate)*Hdim + ot*16 + ll16)*Hdim + kc*32 + lq*8);
    *(int4*)(&wlds[i*8]) = *(const int4*)src;
  }

  int o = ot*16 + l16;
  float br  = bih[k*3*Hdim + o] + bhh[k*3*Hdim + o];
  float bz  = bih[k*3*Hdim + Hdim + o] + bhh[k*3*Hdim + Hdim + o];
  float bnx = bih[k*3*Hdim + 2*Hdim + o];
  float bnh = bhh[k*3*Hdim + 2*Hdim + o];
  float wout = fc_out_W[(k & 1)*Hdim + o];

  // fp32 h state in registers: hk[rb][reg] <-> b = bt*256 + wid*32 + rb*16 + quad*4 + reg
  float hk[2][4];
  #pragma unroll
  for (int rb=0; rb<2; ++rb)
    #pragma unroll
    for (int reg=0; reg<4; ++reg)
      hk[rb][reg] = init_h[(bt*256 + wid*32 + rb*16 + quad*4 + reg)*Hdim + o];

  __syncthreads();

  // one GEMM side: 16 K32 chunks starting at phase `rot`, depth-4 A prefetch from
  // global, depth-1 B from LDS; per wave 2 row-blocks (32 b-rows)
  #define GEMM_SIDE(SIDE, ABASE, NACC) do {                                     \
    const short* ap_[2];                                                        \
    _Pragma("unroll")                                                           \
    for (int rb=0; rb<2; ++rb)                                                  \
      ap_[rb] = (ABASE) + (wid*32 + rb*16 + l16)*Hdim + quad*8;                 \
    short8 ab_[4][2];                                                           \
    _Pragma("unroll")                                                           \
    for (int d=0; d<4; ++d)                                                     \
      _Pragma("unroll")                                                         \
      for (int rb=0; rb<2; ++rb)                                                \
        ab_[d][rb] = *(const short8*)(ap_[rb] + ((d + rot) & 15)*32);           \
    short8 bb_[2][3];                                                           \
    _Pragma("unroll")                                                           \
    for (int g=0; g<3; ++g)                                                     \
      bb_[0][g] = *(const short8*)(&wlds[((((SIDE)*3+g)*16 + rot)<<9) + (lane<<3)]); \
    _Pragma("unroll")                                                           \
    for (int kc=0; kc<16; ++kc){                                                \
      short8 acur_[2];                                                          \
      _Pragma("unroll")                                                         \
      for (int rb=0; rb<2; ++rb) acur_[rb] = ab_[kc&3][rb];                     \
      if (kc < 12){                                                             \
        _Pragma("unroll")                                                       \
        for (int rb=0; rb<2; ++rb)                                              \
          ab_[kc&3][rb] = *(const short8*)(ap_[rb] + ((kc + 4 + rot) & 15)*32); \
      }                                                                         \
      if (kc < 15){                                                             \
        _Pragma("unroll")                                                       \
        for (int g=0; g<3; ++g)                                                 \
          bb_[(kc+1)&1][g] =                                                    \
            *(const short8*)(&wlds[((((SIDE)*3+g)*16 + ((kc + 1 + rot) & 15))<<9) + (lane<<3)]); \
      }                                                                         \
      _Pragma("unroll")                                                         \
      for (int rb=0; rb<2; ++rb){                                               \
        acc_r[rb] = __builtin_amdgcn_mfma_f32_16x16x32_bf16(acur_[rb], bb_[kc&1][0], acc_r[rb], 0,0,0); \
        acc_z[rb] = __builtin_amdgcn_mfma_f32_16x16x32_bf16(acur_[rb], bb_[kc&1][1], acc_z[rb], 0,0,0); \
        acc_n[NACC][rb] = __builtin_amdgcn_mfma_f32_16x16x32_bf16(acur_[rb], bb_[kc&1][2], acc_n[NACC][rb], 0,0,0); \
      }                                                                         \
    }                                                                           \
  } while(0)

  for (int s = 0; s < 64; ++s){
    const bf16* h_in  = (s & 1) ? h_b0 : h_b1;   // H[s-1] lives in buf[(s-1)&1]
    bf16*       h_out = (s & 1) ? h_b1 : h_b0;   // H[s]   goes to buf[s&1]

    f32x4 acc_r[2], acc_z[2], acc_n[2][2];
    #pragma unroll
    for (int rb=0; rb<2; ++rb){
      acc_r[rb]=(f32x4){0.f,0.f,0.f,0.f}; acc_z[rb]=(f32x4){0.f,0.f,0.f,0.f};
      acc_n[0][rb]=(f32x4){0.f,0.f,0.f,0.f}; acc_n[1][rb]=(f32x4){0.f,0.f,0.f,0.f};
    }

    // ---- x-side (independent of other blocks; overlaps others' step-(s-1) tail) ----
    const short* x_base = (const short*)(x_seq + ((size_t)(s*NC + k)*Bdim + bt*256)*Hdim);
    GEMM_SIDE(0, x_base, 0);

    // ---- wait: all 32 block counters >= s. 32-lane relaxed atomic-LOAD poll
    //      (agent scope bypasses L1; loads don't serialize like RMWs). ----
    if (s){
      if (wid == 0){
        int guard = 0;
        for (;;){
          unsigned v = (lane < 32)
            ? __hip_atomic_load(&gflags[lane], __ATOMIC_RELAXED, __HIP_MEMORY_SCOPE_AGENT)
            : 0xFFFFFFFFu;
          if (__ballot(v >= (unsigned)s) == ~0ull) break;
          __builtin_amdgcn_s_sleep(2);
          if (++guard > 2000000) break;
        }
      }
      __syncthreads();   // also the compiler memory barrier for the h loads below
    }

    // ---- h-side ----
    const short* h_base = (const short*)(h_in + (size_t)(k*Bdim + bt*256)*Hdim);
    GEMM_SIDE(1, h_base, 1);

    // ---- epilogue: gates, register h update, bf16 shadow store, partial dot ----
    int tmap = (k < 2) ? s : (Tdim - 1 - s);
    #pragma unroll
    for (int rb = 0; rb < 2; ++rb){
      #pragma unroll
      for (int reg = 0; reg < 4; ++reg){
        int b = bt*256 + wid*32 + rb*16 + quad*4 + reg;
        float r = sigmoidf_(acc_r[rb][reg] + br);
        float z = sigmoidf_(acc_z[rb][reg] + bz);
        float n = tanhf_(acc_n[0][rb][reg] + bnx + r*(acc_n[1][rb][reg] + bnh));
        float hn = (1.f - z)*n + z*hk[rb][reg];
        hk[rb][reg] = hn;
        h_out[(size_t)(k*Bdim + b)*Hdim + o] = (bf16)hn;
        float v = hn * wout;
        v += __shfl_xor(v, 1, 64);
        v += __shfl_xor(v, 2, 64);
        v += __shfl_xor(v, 4, 64);
        v += __shfl_xor(v, 8, 64);
        if (l16 == 0) part[((k*Tdim + tmap)*Bdim + b)*32 + ot] = v;
      }
    }

    // ---- signal: __syncthreads drains vmcnt(0) for all waves (h in local L2),
    //      then bump own counter with one relaxed RMW ----
    if (s < 63){
      __syncthreads();
      if (tid == 0)
        __hip_atomic_fetch_add(&gflags[ot], 1u,
                               __ATOMIC_RELAXED, __HIP_MEMORY_SCOPE_AGENT);
    }
  }
  #undef GEMM_SIDE
}

// ---------------- out[head][b][t] = bias + sum over {head,head+2} x 32 ot-partials ----
__global__ __launch_bounds__(256) void finalize_kernel(const float* __restrict__ part,
                                const float* __restrict__ fc_out_b, float* __restrict__ out){
  int idx = blockIdx.x*256 + threadIdx.x;  // 0..65535
  int head = idx >> 15;
  int b = (idx >> 6) & 511;
  int t = idx & 63;
  float v = fc_out_b[head];
  #pragma unroll
  for (int kk = 0; kk < 2; ++kk){
    const float* p = part + (((head + kk*2)*Tdim + t)*Bdim + b)*32;
    #pragma unroll
    for (int j = 0; j < 8; ++j){
      float4 f = *(const float4*)(p + j*4);
      v += f.x + f.y + f.z + f.w;
    }
  }
  out[idx] = v;
}

extern "C" void kernel_launch(void* const* d_in, const int* in_sizes, int n_in,
                              void* d_out, int out_size, void* d_ws, size_t ws_size,
                              hipStream_t stream){
  (void)in_sizes; (void)n_in; (void)out_size; (void)ws_size;
  const float* data     = (const float*)d_in[0];
  const float* init_h   = (const float*)d_in[1];
  const float* fc_in_W  = (const float*)d_in[2];
  const float* fc_in_b  = (const float*)d_in[3];
  const float* Wih      = (const float*)d_in[4];
  const float* Whh      = (const float*)d_in[5];
  const float* bih      = (const float*)d_in[6];
  const float* bhh      = (const float*)d_in[7];
  const float* fc_out_W = (const float*)d_in[8];
  const float* fc_out_b = (const float*)d_in[9];
  float* out = (float*)d_out;

  char* ws = (char*)d_ws;
  bf16*  x_seq   = (bf16*)ws;                     // [T][K][B][H] bf16 : 134217728 B
  bf16*  h_b0    = (bf16*)(ws + 134217728);       // [K][B][H]  bf16 :   2097152 B
  bf16*  h_b1    = (bf16*)(ws + 136314880);       //                     2097152 B
  float* part    = (float*)(ws + 138412032);      // [K][T][B][32] f32:  16777216 B
  bf16*  dataT   = (bf16*)(ws + 138412032);       // overlay (dead before rnn): 4 MB
  bf16*  fcW_bf  = (bf16*)(ws + 142606336);       // overlay (dead before rnn): 256 KB
  bf16*  Wih_bf  = (bf16*)(ws + 155189248);       // [K][3H][H] bf16 :   6291456 B
  bf16*  Whh_bf  = (bf16*)(ws + 161480704);       //                     6291456 B
  unsigned* flags= (unsigned*)(ws + 167772160);   // [8][32] u32 = 1024 B (line/XCD)
  unsigned* xslot= (unsigned*)(ws + 167773184);   // [8][32] u32 = 1024 B (128B stride)

  const int nW  = NC*3*Hdim*Hdim;   // 3,145,728
  const int nFW = NC*Hdim*Fdim;     //   131,072
  hipLaunchKernelGGL(pack_kernel, dim3(nW/1024),  dim3(256), 0, stream, Wih, Wih_bf, nW);
  hipLaunchKernelGGL(pack_kernel, dim3(nW/1024),  dim3(256), 0, stream, Whh, Whh_bf, nW);
  hipLaunchKernelGGL(pack_kernel, dim3(nFW/1024), dim3(256), 0, stream, fc_in_W, fcW_bf, nFW);
  hipLaunchKernelGGL(init_kernel, dim3(4096), dim3(256), 0, stream, init_h, h_b1, flags);
  hipLaunchKernelGGL(transpose_kernel, dim3(512), dim3(256), 0, stream, data, dataT);
  hipLaunchKernelGGL(proj_kernel, dim3(8192), dim3(256), 0, stream, dataT, fcW_bf, fc_in_b, x_seq);
  hipLaunchKernelGGL(rnn_kernel, dim3(256), dim3(512), 0, stream,
      x_seq, init_h, h_b0, h_b1, Wih_bf, Whh_bf, bih, bhh, fc_out_W, part, flags, xslot);
  hipLaunchKernelGGL(finalize_kernel, dim3(256), dim3(256), 0, stream, part, fc_out_b, out);
}